// Round 9
// baseline (568.217 us; speedup 1.0000x reference)
//
#include <hip/hip_runtime.h>
#include <hip/hip_bf16.h>
#include <stdint.h>

// Problem dims (SMC transformer, noise=False => causal self-attention)
#define BB 8
#define SS 2048
#define TT (BB*SS)       // 16384 tokens total (P=1)
#define DD 512
#define DFFX 2048

static __device__ const float SQRTD  = 22.627416997969522f;   // sqrt(512)
static __device__ const float INVSQD = 0.04419417382415922f;  // 1/sqrt(512)

typedef __attribute__((ext_vector_type(4))) float  f32x4_t;
typedef __attribute__((ext_vector_type(8))) __bf16 bf16x8_t;
typedef __attribute__((ext_vector_type(4))) __bf16 bf16x4_t;
typedef __attribute__((ext_vector_type(2))) __bf16 bf16x2_t;

// MFMA 16x16x32 bf16 operand layout (gfx950), HW-verified rounds 1-8:
//   A: lane l, elem e -> A[l&15][4*(l>>4) + (e&3) + 16*(e>>2)]
//   B: lane l, elem e -> B[4*(l>>4) + (e&3) + 16*(e>>2)][l&15]
//   D: lane l, reg  r -> D[4*(l>>4) + r][l&15]
static __device__ __forceinline__ bf16x8_t mk_frag(bf16x4_t lo, bf16x4_t hi) {
  return __builtin_shufflevector(lo, hi, 0, 1, 2, 3, 4, 5, 6, 7);
}

// async global->LDS, 16B per lane, dest = uniform base + lane*16
typedef __attribute__((address_space(1))) const unsigned int g_u32;
typedef __attribute__((address_space(3))) unsigned int lds_u32;
static __device__ __forceinline__ void gld16(const void* g, void* l) {
  __builtin_amdgcn_global_load_lds((g_u32*)g, (lds_u32*)l, 16, 0, 0);
}

// ---------------- merged weight transpose+convert for Wo/Wf1/Wf2:
// dst[C][R] (bf16) = src[R][C] (f32); 2304 blocks, segment decoded from bx.
__global__ __launch_bounds__(256) void transpose_conv3(
    const float* __restrict__ Wo, const float* __restrict__ Wf1,
    const float* __restrict__ Wf2, __bf16* __restrict__ Wo_t,
    __bf16* __restrict__ Wf1_t, __bf16* __restrict__ Wf2_t) {
  const int bx = blockIdx.x;
  const float* src; __bf16* dst; int C, R, gx, gy;
  if (bx < 256)       { src = Wo;  dst = Wo_t;  R = 512;  C = 512;  gx = bx & 15;  gy = bx >> 4; }
  else if (bx < 1280) { const int b = bx - 256;  src = Wf1; dst = Wf1_t; R = 512;  C = 2048; gx = b & 63; gy = b >> 6; }
  else                { const int b = bx - 1280; src = Wf2; dst = Wf2_t; R = 2048; C = 512;  gx = b & 15; gy = b >> 4; }
  __shared__ float tile[32][33];
  const int c0 = gx * 32, r0 = gy * 32;
  const int tx = threadIdx.x & 31, ty = threadIdx.x >> 5;
#pragma unroll
  for (int i = 0; i < 4; i++)
    tile[ty + 8*i][tx] = src[(size_t)(r0 + ty + 8*i) * C + c0 + tx];
  __syncthreads();
#pragma unroll
  for (int i = 0; i < 4; i++)
    dst[(size_t)(c0 + ty + 8*i) * R + r0 + tx] = (__bf16)tile[tx][ty + 8*i];
}

// ---------------- fold: Wfold[r][c] = sqrt(d) * (Wp @ W{q,k,v})[r][c]  (16x1536)
//                  bfold[c] = sqrt(d) * (bp @ W)[c] + b[c]
__global__ __launch_bounds__(256) void fold_kernel(
    const float* __restrict__ Wp, const float* __restrict__ bp,
    const float* __restrict__ Wq, const float* __restrict__ bq,
    const float* __restrict__ Wk, const float* __restrict__ bk,
    const float* __restrict__ Wv, const float* __restrict__ bv,
    float* __restrict__ Wfold, float* __restrict__ bfold) {
  __shared__ float wp[16][512];
  __shared__ float bps[512];
  for (int i = threadIdx.x; i < 16 * 512; i += 256) wp[i >> 9][i & 511] = Wp[i];
  for (int i = threadIdx.x; i < 512; i += 256) bps[i] = bp[i];
  __syncthreads();
  const int cl = threadIdx.x & 15, r = threadIdx.x >> 4;
  const int cg = blockIdx.x * 16 + cl;           // 0..1535
  const int sub = cg >> 9, wc = cg & 511;        // uniform per block
  const float* W = sub == 0 ? Wq : sub == 1 ? Wk : Wv;
  const float* bb = sub == 0 ? bq : sub == 1 ? bk : bv;
  float acc = 0.f, bacc = 0.f;
  for (int k = 0; k < 512; k += 4) {
    const float4 wpv = *(const float4*)&wp[r][k];
    const float g0 = W[(size_t)k * 512 + wc];
    const float g1 = W[(size_t)(k + 1) * 512 + wc];
    const float g2 = W[(size_t)(k + 2) * 512 + wc];
    const float g3 = W[(size_t)(k + 3) * 512 + wc];
    acc += wpv.x * g0 + wpv.y * g1 + wpv.z * g2 + wpv.w * g3;
    if (r == 0) {
      const float4 b4 = *(const float4*)&bps[k];
      bacc += b4.x * g0 + b4.y * g1 + b4.z * g2 + b4.w * g3;
    }
  }
  Wfold[(size_t)r * 1536 + cg] = acc * SQRTD;
  if (r == 0) bfold[cg] = bacc * SQRTD + bb[wc];
}

// ---------------- small-K (K=16) dense, 4 slices: sl 0/1/2 = q/k/v via Wfold
// (ldw=1536), sl 3 = x via Wp (ldw=512, scale=sqrt(d)). 16 tokens/block;
// thread owns 2 cols with the 16x2 weight block in VGPRs.
__global__ __launch_bounds__(256) void smallk_kernel(
    const float* __restrict__ inp,
    const float* __restrict__ Wfold, const float* __restrict__ bfold,
    const float* __restrict__ Wp, const float* __restrict__ bp,
    __bf16* __restrict__ qb, __bf16* __restrict__ kb, __bf16* __restrict__ vb,
    __bf16* __restrict__ xb, float* __restrict__ o_k, float* __restrict__ o_v) {
  const int sl = blockIdx.y;
  const float* W; const float* bias; int ldw; float scale;
  __bf16* ob; float* fo;
  if (sl == 3) { W = Wp; bias = bp; ldw = 512; scale = SQRTD; ob = xb; fo = nullptr; }
  else {
    W = Wfold + sl * 512; bias = bfold + sl * 512; ldw = 1536; scale = 1.f;
    ob = sl == 0 ? qb : sl == 1 ? kb : vb;
    fo = sl == 0 ? (float*)nullptr : sl == 1 ? o_k : o_v;
  }
  __shared__ float ivl[16][16];
  const int tid = threadIdx.x;
  ivl[tid >> 4][tid & 15] = inp[(size_t)blockIdx.x * 256 + tid];
  const int c0 = 2 * tid;
  float w0[16], w1[16];
#pragma unroll
  for (int r = 0; r < 16; r++) {
    w0[r] = W[(size_t)r * ldw + c0];
    w1[r] = W[(size_t)r * ldw + c0 + 1];
  }
  const float bb0 = bias[c0], bb1 = bias[c0 + 1];
  __syncthreads();
#pragma unroll 4
  for (int tt = 0; tt < 16; ++tt) {
    const float4 i0 = *(const float4*)&ivl[tt][0];
    const float4 i1 = *(const float4*)&ivl[tt][4];
    const float4 i2 = *(const float4*)&ivl[tt][8];
    const float4 i3 = *(const float4*)&ivl[tt][12];
    float a0, a1;
    a0  = i0.x * w0[0];   a1  = i0.x * w1[0];
    a0 += i0.y * w0[1];   a1 += i0.y * w1[1];
    a0 += i0.z * w0[2];   a1 += i0.z * w1[2];
    a0 += i0.w * w0[3];   a1 += i0.w * w1[3];
    a0 += i1.x * w0[4];   a1 += i1.x * w1[4];
    a0 += i1.y * w0[5];   a1 += i1.y * w1[5];
    a0 += i1.z * w0[6];   a1 += i1.z * w1[6];
    a0 += i1.w * w0[7];   a1 += i1.w * w1[7];
    a0 += i2.x * w0[8];   a1 += i2.x * w1[8];
    a0 += i2.y * w0[9];   a1 += i2.y * w1[9];
    a0 += i2.z * w0[10];  a1 += i2.z * w1[10];
    a0 += i2.w * w0[11];  a1 += i2.w * w1[11];
    a0 += i3.x * w0[12];  a1 += i3.x * w1[12];
    a0 += i3.y * w0[13];  a1 += i3.y * w1[13];
    a0 += i3.z * w0[14];  a1 += i3.z * w1[14];
    a0 += i3.w * w0[15];  a1 += i3.w * w1[15];
    const float v0 = (a0 + bb0) * scale;
    const float v1 = (a1 + bb1) * scale;
    const size_t t = (size_t)blockIdx.x * 16 + tt;
    bf16x2_t pv; pv[0] = (__bf16)v0; pv[1] = (__bf16)v1;
    *(bf16x2_t*)(ob + t * 512 + c0) = pv;
    if (fo) {
      float2 fv; fv.x = v0; fv.y = v1;
      *(float2*)(fo + t * 512 + c0) = fv;
    }
  }
}

// ---------------- 128-row MFMA GEMM, 3-buffer ring + counted vmcnt (T4).
// WIDE: output 128x256 per block (2 n-halves share one A-tile) -> 32 MFMA per
// barrier window instead of 16; B staging 4 gld/wave; vmcnt 12/6/0.
// CTRI: skip blocks with n0 > m0+127.  CAUSAL: k-loop ends at m0+128 (PV).
// RELU: relu(acc+bias).  RES: += Res[cOff + row*N + col].  SCALE: *= 1/sqrt(D).
// CT: store transposed Cb[cOff + col*SS + row].
// PAIR (with CAUSAL): block handles m-blocks blockIdx.y and 2*gridDim.y-1-y.
template <bool CTRI, bool CAUSAL, bool RELU, bool RES, bool SCALE, bool CT,
          bool PAIR, bool WIDE>
__global__ __launch_bounds__(256) void gemm128(
    const __bf16* __restrict__ A, const __bf16* __restrict__ Bt,
    const float* __restrict__ bias, const __bf16* __restrict__ Res,
    __bf16* __restrict__ Cb, float* __restrict__ Cf,
    int N, int K, size_t aBatch, size_t bBatch, size_t cBatch) {
  constexpr int NH  = WIDE ? 2 : 1;      // n-halves
  constexpr int NBQ = WIDE ? 4 : 2;      // B gld calls per wave per K-step
  constexpr int BSTRIDE = WIDE ? 16384 : 8192;   // Bs bytes per ring buffer
  const int n0 = blockIdx.x * (WIDE ? 256 : 128);
  if (CTRI && !PAIR && n0 > (int)blockIdx.y * 128 + 127) return;
  __shared__ __align__(16) __bf16 As[3 * 128 * 32];
  __shared__ __align__(16) __bf16 Bs[WIDE ? 3 * 256 * 32 : 3 * 128 * 32];
  const int tid = threadIdx.x, lane = tid & 63, wave = tid >> 6;
  const int l15 = lane & 15, g = lane >> 4;
  const int wr = wave >> 1, wc = wave & 1;

  // staging decode: row = base + q*16 + (lane>>2); physical chunk = lane&3;
  // source logical chunk = (lane&3) ^ ((row>>1)&3). Since base%32==0 and
  // q*16 doesn't touch row bits 1-2, the XOR term = (lane>>3)&3 for ALL q.
  const int sc = (((lane & 3) ^ ((lane >> 3) & 3)) << 4);
  const size_t aOff = (size_t)blockIdx.z * aBatch;
  const size_t bOff = (size_t)blockIdx.z * bBatch;
  const size_t cOff = (size_t)blockIdx.z * cBatch;
  const char* gb[NBQ];
#pragma unroll
  for (int q = 0; q < NBQ; q++)
    gb[q] = (const char*)(Bt + bOff +
            (size_t)(n0 + wave * (WIDE ? 64 : 32) + q * 16 + (lane >> 2)) * K) + sc;

  // frag-read byte offsets (linear+swizzled LDS): phys chunk = logical ^
  // ((l15>>1)&3); hi half = lo addr ^ 32. Row bits 1-2 come only from l15.
  const int plo = (g >> 1) ^ ((l15 >> 1) & 3);
  const int aof0 = (wr * 64 + l15) * 64 + plo * 16 + (g & 1) * 8;
  const int bof0 = (wc * 64 + l15) * 64 + plo * 16 + (g & 1) * 8;

  const int nhalf = PAIR ? 2 : 1;
#pragma unroll
  for (int half = 0; half < nhalf; ++half) {
    const int mb = (half == 0) ? (int)blockIdx.y
                               : (2 * (int)gridDim.y - 1 - (int)blockIdx.y);
    const int m0 = mb * 128;
    const char* ga0 = (const char*)(A + aOff +
        (size_t)(m0 + wave * 32 + (lane >> 2)) * K) + sc;
    const char* ga1 = ga0 + (size_t)16 * K * 2;

    f32x4_t acc[4][4][NH];
#pragma unroll
    for (int i = 0; i < 4; i++)
#pragma unroll
      for (int j = 0; j < 4; j++)
#pragma unroll
        for (int h = 0; h < NH; h++) acc[i][j][h] = (f32x4_t){0.f, 0.f, 0.f, 0.f};

    auto STAGE = [&](const int buf, const int k0) {
      const size_t kb = (size_t)k0 * 2;
      char* la = (char*)As + buf * 8192 + wave * 2048;
      gld16(ga0 + kb, la);
      gld16(ga1 + kb, la + 1024);
      char* lb = (char*)Bs + buf * BSTRIDE + wave * (WIDE ? 4096 : 2048);
#pragma unroll
      for (int q = 0; q < NBQ; q++) gld16(gb[q] + kb, lb + q * 1024);
    };
    auto COMPUTE = [&](const int buf) {
      const char* AsB = (const char*)As + buf * 8192;
      const char* BsB = (const char*)Bs + buf * BSTRIDE;
      bf16x8_t af[4], bfr[4][NH];
#pragma unroll
      for (int i = 0; i < 4; i++) {
        const int ao = aof0 + i * 1024;
        af[i] = mk_frag(*(const bf16x4_t*)(AsB + ao),
                        *(const bf16x4_t*)(AsB + (ao ^ 32)));
      }
#pragma unroll
      for (int h = 0; h < NH; h++)
#pragma unroll
        for (int j = 0; j < 4; j++) {
          const int bo = bof0 + j * 1024 + h * 8192;
          bfr[j][h] = mk_frag(*(const bf16x4_t*)(BsB + bo),
                              *(const bf16x4_t*)(BsB + (bo ^ 32)));
        }
#pragma unroll
      for (int h = 0; h < NH; h++)
#pragma unroll
        for (int i = 0; i < 4; i++)
#pragma unroll
          for (int j = 0; j < 4; j++)
            acc[i][j][h] = __builtin_amdgcn_mfma_f32_16x16x32_bf16(
                af[i], bfr[j][h], acc[i][j][h], 0, 0, 0);
    };

    const int kend = CAUSAL ? (m0 + 128) : K;
    const int nt = kend >> 5;           // >= 4 at every call site
    STAGE(0, 0);
    STAGE(1, 32);
    STAGE(2, 64);
    int cur = 0;
    for (int t = 0; t < nt; ++t) {
      const int rem = nt - 1 - t;
      if (WIDE) {
        if (rem >= 2)      asm volatile("s_waitcnt vmcnt(12)" ::: "memory");
        else if (rem == 1) asm volatile("s_waitcnt vmcnt(6)" ::: "memory");
        else               asm volatile("s_waitcnt vmcnt(0)" ::: "memory");
      } else {
        if (rem >= 2)      asm volatile("s_waitcnt vmcnt(8)" ::: "memory");
        else if (rem == 1) asm volatile("s_waitcnt vmcnt(4)" ::: "memory");
        else               asm volatile("s_waitcnt vmcnt(0)" ::: "memory");
      }
      __builtin_amdgcn_s_barrier();     // tile t visible everywhere
      COMPUTE(cur);
      __builtin_amdgcn_s_barrier();     // all reads of buf `cur` done
      if (t + 3 < nt) STAGE(cur, (t + 3) << 5);
      cur = (cur == 2) ? 0 : cur + 1;
    }

#pragma unroll
    for (int h = 0; h < NH; h++) {
#pragma unroll
      for (int i = 0; i < 4; i++) {
#pragma unroll
        for (int j = 0; j < 4; j++) {
          const int col = n0 + h * 128 + wc * 64 + j * 16 + l15;
          if (CT) {
            // transposed bf16 store: Ct[col][row], 4 contiguous rows/thread
            const int row0 = m0 + wr * 64 + i * 16 + g * 4;
            bf16x4_t tv;
#pragma unroll
            for (int r = 0; r < 4; r++) tv[r] = (__bf16)acc[i][j][h][r];
            *(bf16x4_t*)(Cb + cOff + (size_t)col * SS + row0) = tv;
          } else {
            const float bv = bias ? bias[col] : 0.f;
#pragma unroll
            for (int r = 0; r < 4; r++) {
              const int row = m0 + wr * 64 + i * 16 + g * 4 + r;
              float v = acc[i][j][h][r];
              if (SCALE) v *= INVSQD;
              v += bv;
              if (RELU) v = fmaxf(v, 0.f);
              if (RES) v += (float)Res[cOff + (size_t)row * N + col];
              const size_t cidx = cOff + (size_t)row * N + col;
              if (Cb) Cb[cidx] = (__bf16)v;
              if (Cf) Cf[cidx] = v;
            }
          }
        }
      }
    }
  }
}

// ---------------- row softmax: reads bf16 scores from pb (lower-tri valid),
// writes fp32 probs to att (full row, exact zeros above diag) + bf16 probs
// back into pb in place (only chunks PV will read). One wave per row.
__global__ __launch_bounds__(256) void softmax_kernel(
    float* __restrict__ att, __bf16* __restrict__ pb) {
  const int t = blockIdx.x * 4 + (threadIdx.x >> 6);   // global row (b*2048+q)
  const int gq = t & (SS - 1);                         // query index in batch
  const int lane = threadIdx.x & 63;
  float* row = att + (size_t)t * SS;
  __bf16* prow = pb + (size_t)t * SS;
  const int nch = (gq >> 9) + 1;   // 512-wide chunks containing valid cols
  const int wlim = ((gq & ~127) + 128 + 511) >> 9;
  float x[32];
  float m = -1e30f;
#pragma unroll
  for (int ch = 0; ch < 4; ch++) {
    float* xp = &x[ch * 8];
    if (ch < nch) {
      const int c0 = ch * 512 + lane * 8;
      bf16x8_t v = *(const bf16x8_t*)(prow + c0);
#pragma unroll
      for (int j = 0; j < 8; j++) {
        const float f = (float)v[j];
        xp[j] = (c0 + j <= gq) ? f : -1e30f;  // select: immune to garbage
        m = fmaxf(m, xp[j]);
      }
    } else {
#pragma unroll
      for (int j = 0; j < 8; j++) xp[j] = -1e30f;
    }
  }
#pragma unroll
  for (int off = 1; off < 64; off <<= 1) m = fmaxf(m, __shfl_xor(m, off, 64));
  float s = 0.f;
#pragma unroll
  for (int i = 0; i < 32; i++) { x[i] = __expf(x[i] - m); s += x[i]; }
#pragma unroll
  for (int off = 1; off < 64; off <<= 1) s += __shfl_xor(s, off, 64);
  const float inv = 1.f / s;
#pragma unroll
  for (int ch = 0; ch < 4; ch++) {
    const int c0 = ch * 512 + lane * 8;
    float o[8];
    bf16x8_t ov;
#pragma unroll
    for (int j = 0; j < 8; j++) {
      const float pv = x[ch * 8 + j] * inv;  // masked entries exactly 0
      o[j] = pv;
      ov[j] = (__bf16)pv;
    }
    float4 f0, f1;
    f0.x = o[0]; f0.y = o[1]; f0.z = o[2]; f0.w = o[3];
    f1.x = o[4]; f1.y = o[5]; f1.z = o[6]; f1.w = o[7];
    *(float4*)(row + c0) = f0;
    *(float4*)(row + c0 + 4) = f1;
    if (ch < wlim) *(bf16x8_t*)(prow + c0) = ov;
  }
}

// ---------------- LayerNorm over D=512 (population var, eps inside sqrt)
__global__ __launch_bounds__(256) void ln_kernel(
    const __bf16* __restrict__ X, const float* __restrict__ gam,
    const float* __restrict__ bet, __bf16* __restrict__ Ob, float* __restrict__ Of) {
  const int t = blockIdx.x * 4 + (threadIdx.x >> 6);
  const int lane = threadIdx.x & 63;
  const int d0 = lane * 8;
  bf16x8_t xv = *(const bf16x8_t*)(X + (size_t)t * DD + d0);
  float x[8];
#pragma unroll
  for (int j = 0; j < 8; j++) x[j] = (float)xv[j];
  float s = 0.f, sq = 0.f;
#pragma unroll
  for (int j = 0; j < 8; j++) { s += x[j]; sq += x[j] * x[j]; }
#pragma unroll
  for (int off = 1; off < 64; off <<= 1) {
    s += __shfl_xor(s, off, 64);
    sq += __shfl_xor(sq, off, 64);
  }
  const float mean = s * (1.f / 512.f);
  const float var = sq * (1.f / 512.f) - mean * mean;
  const float rstd = rsqrtf(var + 1e-6f);
  float4 g0 = *(const float4*)(gam + d0), g1v = *(const float4*)(gam + d0 + 4);
  float4 b0 = *(const float4*)(bet + d0), b1v = *(const float4*)(bet + d0 + 4);
  float gg[8] = {g0.x, g0.y, g0.z, g0.w, g1v.x, g1v.y, g1v.z, g1v.w};
  float bb2[8] = {b0.x, b0.y, b0.z, b0.w, b1v.x, b1v.y, b1v.z, b1v.w};
  float o[8];
#pragma unroll
  for (int j = 0; j < 8; j++) o[j] = (x[j] - mean) * rstd * gg[j] + bb2[j];
  if (Ob) {
    bf16x8_t ov;
#pragma unroll
    for (int j = 0; j < 8; j++) ov[j] = (__bf16)o[j];
    *(bf16x8_t*)(Ob + (size_t)t * DD + d0) = ov;
  }
  if (Of) {
    float4 f0; f0.x = o[0]; f0.y = o[1]; f0.z = o[2]; f0.w = o[3];
    float4 f1; f1.x = o[4]; f1.y = o[5]; f1.z = o[6]; f1.w = o[7];
    *(float4*)(Of + (size_t)t * DD + d0) = f0;
    *(float4*)(Of + (size_t)t * DD + d0 + 4) = f1;
  }
}

// ---------------- fused LN2 + final projection:
// r = LN(X) -> o_r (fp32) AND pred = r @ Wfin + bfin -> P1,P2 (no o_r re-read)
__global__ __launch_bounds__(256) void ln_final_kernel(
    const __bf16* __restrict__ X, const float* __restrict__ gam,
    const float* __restrict__ bet, float* __restrict__ Of,
    const float* __restrict__ Wfin, const float* __restrict__ bfin,
    float* __restrict__ P1, float* __restrict__ P2) {
  __shared__ float wfs[512][16];
  __shared__ float rf[4][516];           // +4 pad: de-bank the k-column reads
  for (int i = threadIdx.x; i < 512 * 16; i += 256) wfs[i >> 4][i & 15] = Wfin[i];
  const int tw = threadIdx.x >> 6;       // token slot within block
  const int t = blockIdx.x * 4 + tw;
  const int lane = threadIdx.x & 63;
  const int d0 = lane * 8;
  bf16x8_t xv = *(const bf16x8_t*)(X + (size_t)t * DD + d0);
  float x[8];
#pragma unroll
  for (int j = 0; j < 8; j++) x[j] = (float)xv[j];
  float s = 0.f, sq = 0.f;
#pragma unroll
  for (int j = 0; j < 8; j++) { s += x[j]; sq += x[j] * x[j]; }
#pragma unroll
  for (int off = 1; off < 64; off <<= 1) {
    s += __shfl_xor(s, off, 64);
    sq += __shfl_xor(sq, off, 64);
  }
  const float mean = s * (1.f / 512.f);
  const float var = sq * (1.f / 512.f) - mean * mean;
  const float rstd = rsqrtf(var + 1e-6f);
  float4 g0 = *(const float4*)(gam + d0), g1v = *(const float4*)(gam + d0 + 4);
  float4 b0 = *(const float4*)(bet + d0), b1v = *(const float4*)(bet + d0 + 4);
  float gg[8] = {g0.x, g0.y, g0.z, g0.w, g1v.x, g1v.y, g1v.z, g1v.w};
  float bb2[8] = {b0.x, b0.y, b0.z, b0.w, b1v.x, b1v.y, b1v.z, b1v.w};
  float o[8];
  float4 f0, f1;
#pragma unroll
  for (int j = 0; j < 8; j++) {
    o[j] = (x[j] - mean) * rstd * gg[j] + bb2[j];
    rf[tw][d0 + j] = o[j];
  }
  f0.x = o[0]; f0.y = o[1]; f0.z = o[2]; f0.w = o[3];
  f1.x = o[4]; f1.y = o[5]; f1.z = o[6]; f1.w = o[7];
  *(float4*)(Of + (size_t)t * DD + d0) = f0;
  *(float4*)(Of + (size_t)t * DD + d0 + 4) = f1;
  __syncthreads();
  if (threadIdx.x < 64) {
    const int tt = threadIdx.x >> 4, n = threadIdx.x & 15;
    float acc = 0.f;
#pragma unroll 4
    for (int k = 0; k < 512; k += 4) {
      const float4 rv = *(const float4*)&rf[tt][k];
      acc += rv.x * wfs[k][n] + rv.y * wfs[k + 1][n] +
             rv.z * wfs[k + 2][n] + rv.w * wfs[k + 3][n];
    }
    const float v = acc + bfin[n];
    const size_t tok = (size_t)blockIdx.x * 4 + tt;
    P1[tok * 16 + n] = v;
    P2[tok * 16 + n] = v;
  }
}

extern "C" void kernel_launch(void* const* d_in, const int* in_sizes, int n_in,
                              void* d_out, int out_size, void* d_ws, size_t ws_size,
                              hipStream_t stream) {
  const float* inp  = (const float*)d_in[0];
  const float* Wp   = (const float*)d_in[2];
  const float* bp   = (const float*)d_in[3];
  const float* Wq   = (const float*)d_in[4];
  const float* bq   = (const float*)d_in[5];
  const float* Wk   = (const float*)d_in[6];
  const float* bk   = (const float*)d_in[7];
  const float* Wv   = (const float*)d_in[8];
  const float* bv   = (const float*)d_in[9];
  const float* Wo   = (const float*)d_in[10];
  const float* bo   = (const float*)d_in[11];
  const float* g1   = (const float*)d_in[12];
  const float* be1  = (const float*)d_in[13];
  const float* g2   = (const float*)d_in[14];
  const float* be2  = (const float*)d_in[15];
  const float* Wf1  = (const float*)d_in[16];
  const float* bf1  = (const float*)d_in[17];
  const float* Wf2  = (const float*)d_in[18];
  const float* bf2  = (const float*)d_in[19];
  const float* Wfin = (const float*)d_in[20];
  const float* bfin = (const float*)d_in[21];
  (void)in_sizes; (void)n_in; (void)out_size; (void)ws_size;

  float* out = (float*)d_out;
  float* o_pred1 = out;                    // (B,P,S,16)
  float* o_pred2 = out + 262144;
  float* o_k     = out + 524288;           // (B,P,S,512)
  float* o_v     = out + 8912896;
  float* o_r     = out + 17301504;
  float* o_att   = out + 25690112;         // (B,P,S,S)

  // workspace carve-up (~170 MB)
  char* base = (char*)d_ws;
  size_t off = 0;
  auto takeB = [&](size_t bytes) -> char* {
    char* p = base + off;
    off += (bytes + 255) & ~(size_t)255;
    return p;
  };
  float*  Wfold = (float*)takeB((size_t)16 * 1536 * 4);
  float*  bfold = (float*)takeB((size_t)1536 * 4);
  __bf16* Wo_t  = (__bf16*)takeB((size_t)DD * DD * 2);
  __bf16* Wf1_t = (__bf16*)takeB((size_t)DD * DFFX * 2);
  __bf16* Wf2_t = (__bf16*)takeB((size_t)DD * DFFX * 2);
  __bf16* xb    = (__bf16*)takeB((size_t)TT * DD * 2);
  __bf16* qbuf  = (__bf16*)takeB((size_t)TT * DD * 2);
  __bf16* kbuf  = (__bf16*)takeB((size_t)TT * DD * 2);
  __bf16* vbuf  = (__bf16*)takeB((size_t)TT * DD * 2);
  __bf16* vwt   = (__bf16*)takeB((size_t)TT * DD * 2);   // V@Wo transposed [z][D][S]
  __bf16* h1b   = (__bf16*)takeB((size_t)TT * DD * 2);
  __bf16* lninb = (__bf16*)takeB((size_t)TT * DD * 2);
  __bf16* ffb   = (__bf16*)takeB((size_t)TT * DFFX * 2);
  __bf16* pb    = ffb;  // bf16 scores->probs alias FFN scratch (same element
                        // count; pb dead before FFN1 writes ffb)

  // weights -> bf16 transposed [N][K], one merged launch
  transpose_conv3<<<dim3(2304), 256, 0, stream>>>(Wo, Wf1, Wf2, Wo_t, Wf1_t, Wf2_t);

  // fold Wp into Wq/Wk/Wv:  q|k|v = inp @ Wfold + bfold  (K=16)
  fold_kernel<<<dim3(96), 256, 0, stream>>>(Wp, bp, Wq, bq, Wk, bk, Wv, bv,
                                            Wfold, bfold);

  // q,k,v (+ fp32 o_k/o_v) and x residual, one K=16 launch (4 slices)
  smallk_kernel<<<dim3(TT / 16, 4), 256, 0, stream>>>(
      inp, Wfold, bfold, Wp, bp, qbuf, kbuf, vbuf, xb, o_k, o_v);

  // scores = q @ k^T / sqrt(d) -> bf16 into pb (lower-triangle blocks only)
  gemm128<true, false, false, false, true, false, false, false>
      <<<dim3(16, 16, BB), 256, 0, stream>>>(
      qbuf, kbuf, nullptr, nullptr, pb, nullptr, SS, DD,
      (size_t)SS * DD, (size_t)SS * DD, (size_t)SS * SS);

  // VWo^T = (v @ Wo)^T per batch, transposed store, WIDE (128x256/block)
  gemm128<false, false, false, false, false, true, false, true>
      <<<dim3(2, 16, BB), 256, 0, stream>>>(
      vbuf, Wo_t, nullptr, nullptr, vwt, nullptr, DD, DD,
      (size_t)SS * DD, 0, (size_t)SS * DD);

  // softmax: bf16 scores (pb) -> fp32 probs (o_att, zeros above diag) + bf16 pb
  softmax_kernel<<<dim3(TT / 4), 256, 0, stream>>>(o_att, pb);

  // PV' = P @ VWo + bo + x -> LN1 input (causal k-tile skip, PAIR balance)
  gemm128<false, true, false, true, false, false, true, false>
      <<<dim3(4, 8, BB), 256, 0, stream>>>(
      pb, vwt, bo, xb, lninb, nullptr, DD, SS,
      (size_t)SS * SS, (size_t)DD * SS, (size_t)SS * DD);

  // LN1
  ln_kernel<<<dim3(TT / 4), 256, 0, stream>>>(lninb, g1, be1, h1b, nullptr);

  // FFN, WIDE tiles (FFN1 overwrites ffb/pb — PV' already done)
  gemm128<false, false, true, false, false, false, false, true>
      <<<dim3(8, 128, 1), 256, 0, stream>>>(
      h1b, Wf1_t, bf1, nullptr, ffb, nullptr, DFFX, DD, 0, 0, 0);
  gemm128<false, false, false, true, false, false, false, true>
      <<<dim3(2, 128, 1), 256, 0, stream>>>(
      ffb, Wf2_t, bf2, h1b, lninb, nullptr, DD, DFFX, 0, 0, 0);

  // fused LN2 -> r (fp32 output) + final projection -> pred (both slots)
  ln_final_kernel<<<dim3(TT / 4), 256, 0, stream>>>(
      lninb, g2, be2, o_r, Wfin, bfin, o_pred1, o_pred2);
}

// Round 10
// 467.602 us; speedup vs baseline: 1.2152x; 1.2152x over previous
//
#include <hip/hip_runtime.h>
#include <hip/hip_bf16.h>
#include <stdint.h>

// Problem dims (SMC transformer, noise=False => causal self-attention)
#define BB 8
#define SS 2048
#define TT (BB*SS)       // 16384 tokens total (P=1)
#define DD 512
#define DFFX 2048

static __device__ const float SQRTD  = 22.627416997969522f;   // sqrt(512)
static __device__ const float INVSQD = 0.04419417382415922f;  // 1/sqrt(512)

typedef __attribute__((ext_vector_type(4))) float  f32x4_t;
typedef __attribute__((ext_vector_type(8))) __bf16 bf16x8_t;
typedef __attribute__((ext_vector_type(4))) __bf16 bf16x4_t;
typedef __attribute__((ext_vector_type(2))) __bf16 bf16x2_t;

// MFMA 16x16x32 bf16 operand layout (gfx950), HW-verified rounds 1-8:
//   A: lane l, elem e -> A[l&15][4*(l>>4) + (e&3) + 16*(e>>2)]
//   B: lane l, elem e -> B[4*(l>>4) + (e&3) + 16*(e>>2)][l&15]
//   D: lane l, reg  r -> D[4*(l>>4) + r][l&15]
static __device__ __forceinline__ bf16x8_t mk_frag(bf16x4_t lo, bf16x4_t hi) {
  return __builtin_shufflevector(lo, hi, 0, 1, 2, 3, 4, 5, 6, 7);
}

// async global->LDS, 16B per lane, dest = uniform base + lane*16
typedef __attribute__((address_space(1))) const unsigned int g_u32;
typedef __attribute__((address_space(3))) unsigned int lds_u32;
static __device__ __forceinline__ void gld16(const void* g, void* l) {
  __builtin_amdgcn_global_load_lds((g_u32*)g, (lds_u32*)l, 16, 0, 0);
}

// ---------------- merged weight transpose+convert for Wo/Wf1/Wf2:
// dst[C][R] (bf16) = src[R][C] (f32); 2304 blocks, segment decoded from bx.
__global__ __launch_bounds__(256) void transpose_conv3(
    const float* __restrict__ Wo, const float* __restrict__ Wf1,
    const float* __restrict__ Wf2, __bf16* __restrict__ Wo_t,
    __bf16* __restrict__ Wf1_t, __bf16* __restrict__ Wf2_t) {
  const int bx = blockIdx.x;
  const float* src; __bf16* dst; int C, R, gx, gy;
  if (bx < 256)       { src = Wo;  dst = Wo_t;  R = 512;  C = 512;  gx = bx & 15;  gy = bx >> 4; }
  else if (bx < 1280) { const int b = bx - 256;  src = Wf1; dst = Wf1_t; R = 512;  C = 2048; gx = b & 63; gy = b >> 6; }
  else                { const int b = bx - 1280; src = Wf2; dst = Wf2_t; R = 2048; C = 512;  gx = b & 15; gy = b >> 4; }
  __shared__ float tile[32][33];
  const int c0 = gx * 32, r0 = gy * 32;
  const int tx = threadIdx.x & 31, ty = threadIdx.x >> 5;
#pragma unroll
  for (int i = 0; i < 4; i++)
    tile[ty + 8*i][tx] = src[(size_t)(r0 + ty + 8*i) * C + c0 + tx];
  __syncthreads();
#pragma unroll
  for (int i = 0; i < 4; i++)
    dst[(size_t)(c0 + ty + 8*i) * R + r0 + tx] = (__bf16)tile[tx][ty + 8*i];
}

// ---------------- fold: Wfold[r][c] = sqrt(d) * (Wp @ W{q,k,v})[r][c]  (16x1536)
//                  bfold[c] = sqrt(d) * (bp @ W)[c] + b[c]
__global__ __launch_bounds__(256) void fold_kernel(
    const float* __restrict__ Wp, const float* __restrict__ bp,
    const float* __restrict__ Wq, const float* __restrict__ bq,
    const float* __restrict__ Wk, const float* __restrict__ bk,
    const float* __restrict__ Wv, const float* __restrict__ bv,
    float* __restrict__ Wfold, float* __restrict__ bfold) {
  __shared__ float wp[16][512];
  __shared__ float bps[512];
  for (int i = threadIdx.x; i < 16 * 512; i += 256) wp[i >> 9][i & 511] = Wp[i];
  for (int i = threadIdx.x; i < 512; i += 256) bps[i] = bp[i];
  __syncthreads();
  const int cl = threadIdx.x & 15, r = threadIdx.x >> 4;
  const int cg = blockIdx.x * 16 + cl;           // 0..1535
  const int sub = cg >> 9, wc = cg & 511;        // uniform per block
  const float* W = sub == 0 ? Wq : sub == 1 ? Wk : Wv;
  const float* bb = sub == 0 ? bq : sub == 1 ? bk : bv;
  float acc = 0.f, bacc = 0.f;
  for (int k = 0; k < 512; k += 4) {
    const float4 wpv = *(const float4*)&wp[r][k];
    const float g0 = W[(size_t)k * 512 + wc];
    const float g1 = W[(size_t)(k + 1) * 512 + wc];
    const float g2 = W[(size_t)(k + 2) * 512 + wc];
    const float g3 = W[(size_t)(k + 3) * 512 + wc];
    acc += wpv.x * g0 + wpv.y * g1 + wpv.z * g2 + wpv.w * g3;
    if (r == 0) {
      const float4 b4 = *(const float4*)&bps[k];
      bacc += b4.x * g0 + b4.y * g1 + b4.z * g2 + b4.w * g3;
    }
  }
  Wfold[(size_t)r * 1536 + cg] = acc * SQRTD;
  if (r == 0) bfold[cg] = bacc * SQRTD + bb[wc];
}

// ---------------- small-K (K=16) dense, 4 slices: sl 0/1/2 = q/k/v via Wfold
// (ldw=1536), sl 3 = x via Wp (ldw=512, scale=sqrt(d)). 16 tokens/block;
// thread owns 2 cols with the 16x2 weight block in VGPRs.
__global__ __launch_bounds__(256) void smallk_kernel(
    const float* __restrict__ inp,
    const float* __restrict__ Wfold, const float* __restrict__ bfold,
    const float* __restrict__ Wp, const float* __restrict__ bp,
    __bf16* __restrict__ qb, __bf16* __restrict__ kb, __bf16* __restrict__ vb,
    __bf16* __restrict__ xb, float* __restrict__ o_k, float* __restrict__ o_v) {
  const int sl = blockIdx.y;
  const float* W; const float* bias; int ldw; float scale;
  __bf16* ob; float* fo;
  if (sl == 3) { W = Wp; bias = bp; ldw = 512; scale = SQRTD; ob = xb; fo = nullptr; }
  else {
    W = Wfold + sl * 512; bias = bfold + sl * 512; ldw = 1536; scale = 1.f;
    ob = sl == 0 ? qb : sl == 1 ? kb : vb;
    fo = sl == 0 ? (float*)nullptr : sl == 1 ? o_k : o_v;
  }
  __shared__ float ivl[16][16];
  const int tid = threadIdx.x;
  ivl[tid >> 4][tid & 15] = inp[(size_t)blockIdx.x * 256 + tid];
  const int c0 = 2 * tid;
  float w0[16], w1[16];
#pragma unroll
  for (int r = 0; r < 16; r++) {
    w0[r] = W[(size_t)r * ldw + c0];
    w1[r] = W[(size_t)r * ldw + c0 + 1];
  }
  const float bb0 = bias[c0], bb1 = bias[c0 + 1];
  __syncthreads();
#pragma unroll 4
  for (int tt = 0; tt < 16; ++tt) {
    const float4 i0 = *(const float4*)&ivl[tt][0];
    const float4 i1 = *(const float4*)&ivl[tt][4];
    const float4 i2 = *(const float4*)&ivl[tt][8];
    const float4 i3 = *(const float4*)&ivl[tt][12];
    float a0, a1;
    a0  = i0.x * w0[0];   a1  = i0.x * w1[0];
    a0 += i0.y * w0[1];   a1 += i0.y * w1[1];
    a0 += i0.z * w0[2];   a1 += i0.z * w1[2];
    a0 += i0.w * w0[3];   a1 += i0.w * w1[3];
    a0 += i1.x * w0[4];   a1 += i1.x * w1[4];
    a0 += i1.y * w0[5];   a1 += i1.y * w1[5];
    a0 += i1.z * w0[6];   a1 += i1.z * w1[6];
    a0 += i1.w * w0[7];   a1 += i1.w * w1[7];
    a0 += i2.x * w0[8];   a1 += i2.x * w1[8];
    a0 += i2.y * w0[9];   a1 += i2.y * w1[9];
    a0 += i2.z * w0[10];  a1 += i2.z * w1[10];
    a0 += i2.w * w0[11];  a1 += i2.w * w1[11];
    a0 += i3.x * w0[12];  a1 += i3.x * w1[12];
    a0 += i3.y * w0[13];  a1 += i3.y * w1[13];
    a0 += i3.z * w0[14];  a1 += i3.z * w1[14];
    a0 += i3.w * w0[15];  a1 += i3.w * w1[15];
    const float v0 = (a0 + bb0) * scale;
    const float v1 = (a1 + bb1) * scale;
    const size_t t = (size_t)blockIdx.x * 16 + tt;
    bf16x2_t pv; pv[0] = (__bf16)v0; pv[1] = (__bf16)v1;
    *(bf16x2_t*)(ob + t * 512 + c0) = pv;
    if (fo) {
      float2 fv; fv.x = v0; fv.y = v1;
      *(float2*)(fo + t * 512 + c0) = fv;
    }
  }
}

// ---------------- 128x128-tile MFMA GEMM, 3-buffer ring + counted vmcnt (T4).
// CTRI: skip blocks with n0 > m0+127.  CAUSAL: k-loop ends at m0+128 (PV).
// RELU: relu(acc+bias).  RES: += Res[cOff + row*N + col].  SCALE: *= 1/sqrt(D).
// CT: store transposed Cb[cOff + col*SS + row].
// PAIR (with CAUSAL): block handles m-blocks blockIdx.y and 2*gridDim.y-1-y.
// XCDS: bijective XCD-chunked remap of (x,y) so all n-blocks of an m-band land
// on ONE XCD -> A-panel becomes an L2 hit after first touch (T1; requires
// gridDim.x*gridDim.y % 8 == 0, z-agnostic since z=1 at XCDS call sites).
template <bool CTRI, bool CAUSAL, bool RELU, bool RES, bool SCALE, bool CT,
          bool PAIR, bool XCDS>
__global__ __launch_bounds__(256) void gemm128(
    const __bf16* __restrict__ A, const __bf16* __restrict__ Bt,
    const float* __restrict__ bias, const __bf16* __restrict__ Res,
    __bf16* __restrict__ Cb, float* __restrict__ Cf,
    int N, int K, size_t aBatch, size_t bBatch, size_t cBatch) {
  int bx = blockIdx.x, by = blockIdx.y;
  if (XCDS) {
    const int nwg = (int)(gridDim.x * gridDim.y);
    const int cpx = nwg >> 3;                     // nwg % 8 == 0 at call sites
    const int lin = (int)(blockIdx.y * gridDim.x + blockIdx.x);
    const int nl = (lin & 7) * cpx + (lin >> 3);  // phys->logical, chunked
    by = nl / (int)gridDim.x;
    bx = nl - by * (int)gridDim.x;
  }
  const int n0 = bx * 128;
  if (CTRI && !PAIR && n0 > by * 128 + 127) return;
  __shared__ __align__(16) __bf16 As[3 * 128 * 32];   // 3 x 8 KB
  __shared__ __align__(16) __bf16 Bs[3 * 128 * 32];
  const int tid = threadIdx.x, lane = tid & 63, wave = tid >> 6;
  const int l15 = lane & 15, g = lane >> 4;
  const int wr = wave >> 1, wc = wave & 1;

  // staging decode: lane's LDS slot = buf*8192 + wave*2048 + lane*16 B.
  // row = wave*32 + q*16 + (lane>>2); physical chunk = lane&3;
  // source logical chunk = (lane&3) ^ ((row>>1)&3)  (XOR involution)
  const int srow0 = wave * 32 + (lane >> 2);
  const int srow1 = srow0 + 16;
  const int sc0 = (((lane & 3) ^ ((srow0 >> 1) & 3)) << 4);
  const int sc1 = (((lane & 3) ^ ((srow1 >> 1) & 3)) << 4);
  const size_t aOff = (size_t)blockIdx.z * aBatch;
  const size_t bOff = (size_t)blockIdx.z * bBatch;
  const size_t cOff = (size_t)blockIdx.z * cBatch;
  const char* gb0 = (const char*)(Bt + bOff + (size_t)(n0 + srow0) * K) + sc0;
  const char* gb1 = (const char*)(Bt + bOff + (size_t)(n0 + srow1) * K) + sc1;

  // frag-read byte offsets (linear+swizzled LDS): phys chunk = logical ^
  // ((l15>>1)&3); hi half = lo addr ^ 32.
  const int plo = (g >> 1) ^ ((l15 >> 1) & 3);
  const int aof0 = (wr * 64 + l15) * 64 + plo * 16 + (g & 1) * 8;
  const int bof0 = (wc * 64 + l15) * 64 + plo * 16 + (g & 1) * 8;

  const int nhalf = PAIR ? 2 : 1;
#pragma unroll
  for (int half = 0; half < nhalf; ++half) {
    const int mb = (half == 0) ? by : (2 * (int)gridDim.y - 1 - by);
    const int m0 = mb * 128;
    const char* ga0 = (const char*)(A + aOff + (size_t)(m0 + srow0) * K) + sc0;
    const char* ga1 = (const char*)(A + aOff + (size_t)(m0 + srow1) * K) + sc1;

    f32x4_t acc[4][4];
#pragma unroll
    for (int i = 0; i < 4; i++)
#pragma unroll
      for (int j = 0; j < 4; j++) acc[i][j] = (f32x4_t){0.f, 0.f, 0.f, 0.f};

    auto STAGE = [&](const int buf, const int k0) {
      const size_t kb = (size_t)k0 * 2;
      char* la = (char*)As + buf * 8192 + wave * 2048;
      char* lb = (char*)Bs + buf * 8192 + wave * 2048;
      gld16(ga0 + kb, la);
      gld16(ga1 + kb, la + 1024);
      gld16(gb0 + kb, lb);
      gld16(gb1 + kb, lb + 1024);
    };
    auto COMPUTE = [&](const int buf) {
      const char* AsB = (const char*)As + buf * 8192;
      const char* BsB = (const char*)Bs + buf * 8192;
      bf16x8_t af[4], bfr[4];
#pragma unroll
      for (int i = 0; i < 4; i++) {
        const int ao = aof0 + i * 1024;
        af[i] = mk_frag(*(const bf16x4_t*)(AsB + ao),
                        *(const bf16x4_t*)(AsB + (ao ^ 32)));
        const int bo = bof0 + i * 1024;
        bfr[i] = mk_frag(*(const bf16x4_t*)(BsB + bo),
                         *(const bf16x4_t*)(BsB + (bo ^ 32)));
      }
#pragma unroll
      for (int i = 0; i < 4; i++)
#pragma unroll
        for (int j = 0; j < 4; j++)
          acc[i][j] = __builtin_amdgcn_mfma_f32_16x16x32_bf16(af[i], bfr[j], acc[i][j], 0, 0, 0);
    };

    const int kend = CAUSAL ? (m0 + 128) : K;
    const int nt = kend >> 5;           // >= 4 at every call site
    STAGE(0, 0);
    STAGE(1, 32);
    STAGE(2, 64);
    int cur = 0;
    for (int t = 0; t < nt; ++t) {
      const int rem = nt - 1 - t;
      if (rem >= 2)      asm volatile("s_waitcnt vmcnt(8)" ::: "memory");
      else if (rem == 1) asm volatile("s_waitcnt vmcnt(4)" ::: "memory");
      else               asm volatile("s_waitcnt vmcnt(0)" ::: "memory");
      __builtin_amdgcn_s_barrier();     // tile t visible everywhere
      COMPUTE(cur);
      __builtin_amdgcn_s_barrier();     // all reads of buf `cur` done
      if (t + 3 < nt) STAGE(cur, (t + 3) << 5);
      cur = (cur == 2) ? 0 : cur + 1;
    }

#pragma unroll
    for (int i = 0; i < 4; i++) {
#pragma unroll
      for (int j = 0; j < 4; j++) {
        const int col = n0 + wc * 64 + j * 16 + l15;
        if (CT) {
          // transposed bf16 store: Ct[col][row], 4 contiguous rows per thread
          const int row0 = m0 + wr * 64 + i * 16 + g * 4;
          bf16x4_t tv;
#pragma unroll
          for (int r = 0; r < 4; r++) tv[r] = (__bf16)acc[i][j][r];
          *(bf16x4_t*)(Cb + cOff + (size_t)col * SS + row0) = tv;
        } else {
          const float bv = bias ? bias[col] : 0.f;
#pragma unroll
          for (int r = 0; r < 4; r++) {
            const int row = m0 + wr * 64 + i * 16 + g * 4 + r;
            float v = acc[i][j][r];
            if (SCALE) v *= INVSQD;
            v += bv;
            if (RELU) v = fmaxf(v, 0.f);
            if (RES) v += (float)Res[cOff + (size_t)row * N + col];
            const size_t cidx = cOff + (size_t)row * N + col;
            if (Cb) Cb[cidx] = (__bf16)v;
            if (Cf) Cf[cidx] = v;
          }
        }
      }
    }
  }
}

// ---------------- row softmax: reads bf16 scores from pb (lower-tri valid),
// writes fp32 probs to att (full row, exact zeros above diag) + bf16 probs
// back into pb in place (only chunks PV will read). One wave per row.
__global__ __launch_bounds__(256) void softmax_kernel(
    float* __restrict__ att, __bf16* __restrict__ pb) {
  const int t = blockIdx.x * 4 + (threadIdx.x >> 6);   // global row (b*2048+q)
  const int gq = t & (SS - 1);                         // query index in batch
  const int lane = threadIdx.x & 63;
  float* row = att + (size_t)t * SS;
  __bf16* prow = pb + (size_t)t * SS;
  const int nch = (gq >> 9) + 1;   // 512-wide chunks containing valid cols
  const int wlim = ((gq & ~127) + 128 + 511) >> 9;
  float x[32];
  float m = -1e30f;
#pragma unroll
  for (int ch = 0; ch < 4; ch++) {
    float* xp = &x[ch * 8];
    if (ch < nch) {
      const int c0 = ch * 512 + lane * 8;
      bf16x8_t v = *(const bf16x8_t*)(prow + c0);
#pragma unroll
      for (int j = 0; j < 8; j++) {
        const float f = (float)v[j];
        xp[j] = (c0 + j <= gq) ? f : -1e30f;  // select: immune to garbage
        m = fmaxf(m, xp[j]);
      }
    } else {
#pragma unroll
      for (int j = 0; j < 8; j++) xp[j] = -1e30f;
    }
  }
#pragma unroll
  for (int off = 1; off < 64; off <<= 1) m = fmaxf(m, __shfl_xor(m, off, 64));
  float s = 0.f;
#pragma unroll
  for (int i = 0; i < 32; i++) { x[i] = __expf(x[i] - m); s += x[i]; }
#pragma unroll
  for (int off = 1; off < 64; off <<= 1) s += __shfl_xor(s, off, 64);
  const float inv = 1.f / s;
#pragma unroll
  for (int ch = 0; ch < 4; ch++) {
    const int c0 = ch * 512 + lane * 8;
    float o[8];
    bf16x8_t ov;
#pragma unroll
    for (int j = 0; j < 8; j++) {
      const float pv = x[ch * 8 + j] * inv;  // masked entries exactly 0
      o[j] = pv;
      ov[j] = (__bf16)pv;
    }
    float4 f0, f1;
    f0.x = o[0]; f0.y = o[1]; f0.z = o[2]; f0.w = o[3];
    f1.x = o[4]; f1.y = o[5]; f1.z = o[6]; f1.w = o[7];
    *(float4*)(row + c0) = f0;
    *(float4*)(row + c0 + 4) = f1;
    if (ch < wlim) *(bf16x8_t*)(prow + c0) = ov;
  }
}

// ---------------- LayerNorm over D=512 (population var, eps inside sqrt)
__global__ __launch_bounds__(256) void ln_kernel(
    const __bf16* __restrict__ X, const float* __restrict__ gam,
    const float* __restrict__ bet, __bf16* __restrict__ Ob, float* __restrict__ Of) {
  const int t = blockIdx.x * 4 + (threadIdx.x >> 6);
  const int lane = threadIdx.x & 63;
  const int d0 = lane * 8;
  bf16x8_t xv = *(const bf16x8_t*)(X + (size_t)t * DD + d0);
  float x[8];
#pragma unroll
  for (int j = 0; j < 8; j++) x[j] = (float)xv[j];
  float s = 0.f, sq = 0.f;
#pragma unroll
  for (int j = 0; j < 8; j++) { s += x[j]; sq += x[j] * x[j]; }
#pragma unroll
  for (int off = 1; off < 64; off <<= 1) {
    s += __shfl_xor(s, off, 64);
    sq += __shfl_xor(sq, off, 64);
  }
  const float mean = s * (1.f / 512.f);
  const float var = sq * (1.f / 512.f) - mean * mean;
  const float rstd = rsqrtf(var + 1e-6f);
  float4 g0 = *(const float4*)(gam + d0), g1v = *(const float4*)(gam + d0 + 4);
  float4 b0 = *(const float4*)(bet + d0), b1v = *(const float4*)(bet + d0 + 4);
  float gg[8] = {g0.x, g0.y, g0.z, g0.w, g1v.x, g1v.y, g1v.z, g1v.w};
  float bb2[8] = {b0.x, b0.y, b0.z, b0.w, b1v.x, b1v.y, b1v.z, b1v.w};
  float o[8];
#pragma unroll
  for (int j = 0; j < 8; j++) o[j] = (x[j] - mean) * rstd * gg[j] + bb2[j];
  if (Ob) {
    bf16x8_t ov;
#pragma unroll
    for (int j = 0; j < 8; j++) ov[j] = (__bf16)o[j];
    *(bf16x8_t*)(Ob + (size_t)t * DD + d0) = ov;
  }
  if (Of) {
    float4 f0; f0.x = o[0]; f0.y = o[1]; f0.z = o[2]; f0.w = o[3];
    float4 f1; f1.x = o[4]; f1.y = o[5]; f1.z = o[6]; f1.w = o[7];
    *(float4*)(Of + (size_t)t * DD + d0) = f0;
    *(float4*)(Of + (size_t)t * DD + d0 + 4) = f1;
  }
}

// ---------------- pred = r @ Wfin + bfin (K=512, N=16), written to both pred slots
__global__ __launch_bounds__(256) void final_kernel(
    const float* __restrict__ Rm, const float* __restrict__ Wfin,
    const float* __restrict__ bfin, float* __restrict__ P1, float* __restrict__ P2) {
  __shared__ float wfs[512][17];
  for (int i = threadIdx.x; i < 512 * 16; i += 256) wfs[i >> 4][i & 15] = Wfin[i];
  __syncthreads();
  const int tl = threadIdx.x >> 4, n = threadIdx.x & 15;
  const int t = blockIdx.x * 16 + tl;
  const float* rp = Rm + (size_t)t * DD;
  float acc = 0.f;
#pragma unroll 4
  for (int k = 0; k < 512; k += 4) {
    float4 rv = *(const float4*)(rp + k);
    acc += rv.x * wfs[k][n] + rv.y * wfs[k + 1][n] + rv.z * wfs[k + 2][n] + rv.w * wfs[k + 3][n];
  }
  const float v = acc + bfin[n];
  P1[(size_t)t * 16 + n] = v;
  P2[(size_t)t * 16 + n] = v;
}

extern "C" void kernel_launch(void* const* d_in, const int* in_sizes, int n_in,
                              void* d_out, int out_size, void* d_ws, size_t ws_size,
                              hipStream_t stream) {
  const float* inp  = (const float*)d_in[0];
  const float* Wp   = (const float*)d_in[2];
  const float* bp   = (const float*)d_in[3];
  const float* Wq   = (const float*)d_in[4];
  const float* bq   = (const float*)d_in[5];
  const float* Wk   = (const float*)d_in[6];
  const float* bk   = (const float*)d_in[7];
  const float* Wv   = (const float*)d_in[8];
  const float* bv   = (const float*)d_in[9];
  const float* Wo   = (const float*)d_in[10];
  const float* bo   = (const float*)d_in[11];
  const float* g1   = (const float*)d_in[12];
  const float* be1  = (const float*)d_in[13];
  const float* g2   = (const float*)d_in[14];
  const float* be2  = (const float*)d_in[15];
  const float* Wf1  = (const float*)d_in[16];
  const float* bf1  = (const float*)d_in[17];
  const float* Wf2  = (const float*)d_in[18];
  const float* bf2  = (const float*)d_in[19];
  const float* Wfin = (const float*)d_in[20];
  const float* bfin = (const float*)d_in[21];
  (void)in_sizes; (void)n_in; (void)out_size; (void)ws_size;

  float* out = (float*)d_out;
  float* o_pred1 = out;                    // (B,P,S,16)
  float* o_pred2 = out + 262144;
  float* o_k     = out + 524288;           // (B,P,S,512)
  float* o_v     = out + 8912896;
  float* o_r     = out + 17301504;
  float* o_att   = out + 25690112;         // (B,P,S,S)

  // workspace carve-up (~170 MB)
  char* base = (char*)d_ws;
  size_t off = 0;
  auto takeB = [&](size_t bytes) -> char* {
    char* p = base + off;
    off += (bytes + 255) & ~(size_t)255;
    return p;
  };
  float*  Wfold = (float*)takeB((size_t)16 * 1536 * 4);
  float*  bfold = (float*)takeB((size_t)1536 * 4);
  __bf16* Wo_t  = (__bf16*)takeB((size_t)DD * DD * 2);
  __bf16* Wf1_t = (__bf16*)takeB((size_t)DD * DFFX * 2);
  __bf16* Wf2_t = (__bf16*)takeB((size_t)DD * DFFX * 2);
  __bf16* xb    = (__bf16*)takeB((size_t)TT * DD * 2);
  __bf16* qbuf  = (__bf16*)takeB((size_t)TT * DD * 2);
  __bf16* kbuf  = (__bf16*)takeB((size_t)TT * DD * 2);
  __bf16* vbuf  = (__bf16*)takeB((size_t)TT * DD * 2);
  __bf16* vwt   = (__bf16*)takeB((size_t)TT * DD * 2);   // V@Wo transposed [z][D][S]
  __bf16* h1b   = (__bf16*)takeB((size_t)TT * DD * 2);
  __bf16* lninb = (__bf16*)takeB((size_t)TT * DD * 2);
  __bf16* ffb   = (__bf16*)takeB((size_t)TT * DFFX * 2);
  __bf16* pb    = ffb;  // bf16 scores->probs alias FFN scratch (same element
                        // count; pb dead before FFN1 writes ffb)

  // weights -> bf16 transposed [N][K], one merged launch
  transpose_conv3<<<dim3(2304), 256, 0, stream>>>(Wo, Wf1, Wf2, Wo_t, Wf1_t, Wf2_t);

  // fold Wp into Wq/Wk/Wv:  q|k|v = inp @ Wfold + bfold  (K=16)
  fold_kernel<<<dim3(96), 256, 0, stream>>>(Wp, bp, Wq, bq, Wk, bk, Wv, bv,
                                            Wfold, bfold);

  // q,k,v (+ fp32 o_k/o_v) and x residual, one K=16 launch (4 slices)
  smallk_kernel<<<dim3(TT / 16, 4), 256, 0, stream>>>(
      inp, Wfold, bfold, Wp, bp, qbuf, kbuf, vbuf, xb, o_k, o_v);

  // scores = q @ k^T / sqrt(d) -> bf16 into pb (lower-triangle blocks only)
  gemm128<true, false, false, false, true, false, false, false>
      <<<dim3(16, 16, BB), 256, 0, stream>>>(
      qbuf, kbuf, nullptr, nullptr, pb, nullptr, SS, DD,
      (size_t)SS * DD, (size_t)SS * DD, (size_t)SS * SS);

  // VWo^T = (v @ Wo)^T per batch, written transposed directly (CT epilogue)
  gemm128<false, false, false, false, false, true, false, false>
      <<<dim3(4, 16, BB), 256, 0, stream>>>(
      vbuf, Wo_t, nullptr, nullptr, vwt, nullptr, DD, DD,
      (size_t)SS * DD, 0, (size_t)SS * DD);

  // softmax: bf16 scores (pb) -> fp32 probs (o_att, zeros above diag) + bf16 pb
  softmax_kernel<<<dim3(TT / 4), 256, 0, stream>>>(o_att, pb);

  // PV' = P @ VWo + bo + x -> LN1 input (causal k-tile skip, PAIR balance)
  gemm128<false, true, false, true, false, false, true, false>
      <<<dim3(4, 8, BB), 256, 0, stream>>>(
      pb, vwt, bo, xb, lninb, nullptr, DD, SS,
      (size_t)SS * SS, (size_t)DD * SS, (size_t)SS * DD);

  // LN1
  ln_kernel<<<dim3(TT / 4), 256, 0, stream>>>(lninb, g1, be1, h1b, nullptr);

  // FFN with XCD-chunked block swizzle (A-panel L2 reuse within XCD)
  gemm128<false, false, true, false, false, false, false, true>
      <<<dim3(16, 128, 1), 256, 0, stream>>>(
      h1b, Wf1_t, bf1, nullptr, ffb, nullptr, DFFX, DD, 0, 0, 0);
  gemm128<false, false, false, true, false, false, false, true>
      <<<dim3(4, 128, 1), 256, 0, stream>>>(
      ffb, Wf2_t, bf2, h1b, lninb, nullptr, DD, DFFX, 0, 0, 0);

  // LN2 -> r (fp32 output), final projection -> pred (written twice)
  ln_kernel<<<dim3(TT / 4), 256, 0, stream>>>(lninb, g2, be2, nullptr, o_r);
  final_kernel<<<dim3(TT / 16), 256, 0, stream>>>(o_r, Wfin, bfin, o_pred1, o_pred2);
}

// Round 11
// 436.609 us; speedup vs baseline: 1.3014x; 1.0710x over previous
//
#include <hip/hip_runtime.h>
#include <hip/hip_bf16.h>
#include <stdint.h>

// Problem dims (SMC transformer, noise=False => causal self-attention)
#define BB 8
#define SS 2048
#define TT (BB*SS)       // 16384 tokens total (P=1)
#define DD 512
#define DFFX 2048

static __device__ const float SQRTD  = 22.627416997969522f;   // sqrt(512)
static __device__ const float INVSQD = 0.04419417382415922f;  // 1/sqrt(512)

typedef __attribute__((ext_vector_type(4))) float  f32x4_t;
typedef __attribute__((ext_vector_type(8))) __bf16 bf16x8_t;
typedef __attribute__((ext_vector_type(4))) __bf16 bf16x4_t;
typedef __attribute__((ext_vector_type(2))) __bf16 bf16x2_t;

// MFMA 16x16x32 bf16 operand layout (gfx950), HW-verified rounds 1-10:
//   A: lane l, elem e -> A[l&15][4*(l>>4) + (e&3) + 16*(e>>2)]
//   B: lane l, elem e -> B[4*(l>>4) + (e&3) + 16*(e>>2)][l&15]
//   D: lane l, reg  r -> D[4*(l>>4) + r][l&15]
static __device__ __forceinline__ bf16x8_t mk_frag(bf16x4_t lo, bf16x4_t hi) {
  return __builtin_shufflevector(lo, hi, 0, 1, 2, 3, 4, 5, 6, 7);
}

// async global->LDS, 16B per lane, dest = uniform base + lane*16
typedef __attribute__((address_space(1))) const unsigned int g_u32;
typedef __attribute__((address_space(3))) unsigned int lds_u32;
static __device__ __forceinline__ void gld16(const void* g, void* l) {
  __builtin_amdgcn_global_load_lds((g_u32*)g, (lds_u32*)l, 16, 0, 0);
}

// ---------------- merged weight transpose+convert for Wo/Wf1/Wf2:
// dst[C][R] (bf16) = src[R][C] (f32); 2304 blocks, segment decoded from bx.
__global__ __launch_bounds__(256) void transpose_conv3(
    const float* __restrict__ Wo, const float* __restrict__ Wf1,
    const float* __restrict__ Wf2, __bf16* __restrict__ Wo_t,
    __bf16* __restrict__ Wf1_t, __bf16* __restrict__ Wf2_t) {
  const int bx = blockIdx.x;
  const float* src; __bf16* dst; int C, R, gx, gy;
  if (bx < 256)       { src = Wo;  dst = Wo_t;  R = 512;  C = 512;  gx = bx & 15;  gy = bx >> 4; }
  else if (bx < 1280) { const int b = bx - 256;  src = Wf1; dst = Wf1_t; R = 512;  C = 2048; gx = b & 63; gy = b >> 6; }
  else                { const int b = bx - 1280; src = Wf2; dst = Wf2_t; R = 2048; C = 512;  gx = b & 15; gy = b >> 4; }
  __shared__ float tile[32][33];
  const int c0 = gx * 32, r0 = gy * 32;
  const int tx = threadIdx.x & 31, ty = threadIdx.x >> 5;
#pragma unroll
  for (int i = 0; i < 4; i++)
    tile[ty + 8*i][tx] = src[(size_t)(r0 + ty + 8*i) * C + c0 + tx];
  __syncthreads();
#pragma unroll
  for (int i = 0; i < 4; i++)
    dst[(size_t)(c0 + ty + 8*i) * R + r0 + tx] = (__bf16)tile[tx][ty + 8*i];
}

// ---------------- fold: Wfold[r][c] = sqrt(d) * (Wp @ W{q,k,v})[r][c]  (16x1536)
//                  bfold[c] = sqrt(d) * (bp @ W)[c] + b[c]
__global__ __launch_bounds__(256) void fold_kernel(
    const float* __restrict__ Wp, const float* __restrict__ bp,
    const float* __restrict__ Wq, const float* __restrict__ bq,
    const float* __restrict__ Wk, const float* __restrict__ bk,
    const float* __restrict__ Wv, const float* __restrict__ bv,
    float* __restrict__ Wfold, float* __restrict__ bfold) {
  __shared__ float wp[16][512];
  __shared__ float bps[512];
  for (int i = threadIdx.x; i < 16 * 512; i += 256) wp[i >> 9][i & 511] = Wp[i];
  for (int i = threadIdx.x; i < 512; i += 256) bps[i] = bp[i];
  __syncthreads();
  const int cl = threadIdx.x & 15, r = threadIdx.x >> 4;
  const int cg = blockIdx.x * 16 + cl;           // 0..1535
  const int sub = cg >> 9, wc = cg & 511;        // uniform per block
  const float* W = sub == 0 ? Wq : sub == 1 ? Wk : Wv;
  const float* bb = sub == 0 ? bq : sub == 1 ? bk : bv;
  float acc = 0.f, bacc = 0.f;
  for (int k = 0; k < 512; k += 4) {
    const float4 wpv = *(const float4*)&wp[r][k];
    const float g0 = W[(size_t)k * 512 + wc];
    const float g1 = W[(size_t)(k + 1) * 512 + wc];
    const float g2 = W[(size_t)(k + 2) * 512 + wc];
    const float g3 = W[(size_t)(k + 3) * 512 + wc];
    acc += wpv.x * g0 + wpv.y * g1 + wpv.z * g2 + wpv.w * g3;
    if (r == 0) {
      const float4 b4 = *(const float4*)&bps[k];
      bacc += b4.x * g0 + b4.y * g1 + b4.z * g2 + b4.w * g3;
    }
  }
  Wfold[(size_t)r * 1536 + cg] = acc * SQRTD;
  if (r == 0) bfold[cg] = bacc * SQRTD + bb[wc];
}

// ---------------- small-K (K=16) dense, 4 slices: sl 0/1/2 = q/k/v via Wfold
// (ldw=1536), sl 3 = x via Wp (ldw=512, scale=sqrt(d)). 16 tokens/block;
// thread owns 2 cols with the 16x2 weight block in VGPRs.
__global__ __launch_bounds__(256) void smallk_kernel(
    const float* __restrict__ inp,
    const float* __restrict__ Wfold, const float* __restrict__ bfold,
    const float* __restrict__ Wp, const float* __restrict__ bp,
    __bf16* __restrict__ qb, __bf16* __restrict__ kb, __bf16* __restrict__ vb,
    __bf16* __restrict__ xb, float* __restrict__ o_k, float* __restrict__ o_v) {
  const int sl = blockIdx.y;
  const float* W; const float* bias; int ldw; float scale;
  __bf16* ob; float* fo;
  if (sl == 3) { W = Wp; bias = bp; ldw = 512; scale = SQRTD; ob = xb; fo = nullptr; }
  else {
    W = Wfold + sl * 512; bias = bfold + sl * 512; ldw = 1536; scale = 1.f;
    ob = sl == 0 ? qb : sl == 1 ? kb : vb;
    fo = sl == 0 ? (float*)nullptr : sl == 1 ? o_k : o_v;
  }
  __shared__ float ivl[16][16];
  const int tid = threadIdx.x;
  ivl[tid >> 4][tid & 15] = inp[(size_t)blockIdx.x * 256 + tid];
  const int c0 = 2 * tid;
  float w0[16], w1[16];
#pragma unroll
  for (int r = 0; r < 16; r++) {
    w0[r] = W[(size_t)r * ldw + c0];
    w1[r] = W[(size_t)r * ldw + c0 + 1];
  }
  const float bb0 = bias[c0], bb1 = bias[c0 + 1];
  __syncthreads();
#pragma unroll 4
  for (int tt = 0; tt < 16; ++tt) {
    const float4 i0 = *(const float4*)&ivl[tt][0];
    const float4 i1 = *(const float4*)&ivl[tt][4];
    const float4 i2 = *(const float4*)&ivl[tt][8];
    const float4 i3 = *(const float4*)&ivl[tt][12];
    float a0, a1;
    a0  = i0.x * w0[0];   a1  = i0.x * w1[0];
    a0 += i0.y * w0[1];   a1 += i0.y * w1[1];
    a0 += i0.z * w0[2];   a1 += i0.z * w1[2];
    a0 += i0.w * w0[3];   a1 += i0.w * w1[3];
    a0 += i1.x * w0[4];   a1 += i1.x * w1[4];
    a0 += i1.y * w0[5];   a1 += i1.y * w1[5];
    a0 += i1.z * w0[6];   a1 += i1.z * w1[6];
    a0 += i1.w * w0[7];   a1 += i1.w * w1[7];
    a0 += i2.x * w0[8];   a1 += i2.x * w1[8];
    a0 += i2.y * w0[9];   a1 += i2.y * w1[9];
    a0 += i2.z * w0[10];  a1 += i2.z * w1[10];
    a0 += i2.w * w0[11];  a1 += i2.w * w1[11];
    a0 += i3.x * w0[12];  a1 += i3.x * w1[12];
    a0 += i3.y * w0[13];  a1 += i3.y * w1[13];
    a0 += i3.z * w0[14];  a1 += i3.z * w1[14];
    a0 += i3.w * w0[15];  a1 += i3.w * w1[15];
    const float v0 = (a0 + bb0) * scale;
    const float v1 = (a1 + bb1) * scale;
    const size_t t = (size_t)blockIdx.x * 16 + tt;
    bf16x2_t pv; pv[0] = (__bf16)v0; pv[1] = (__bf16)v1;
    *(bf16x2_t*)(ob + t * 512 + c0) = pv;
    if (fo) {
      float2 fv; fv.x = v0; fv.y = v1;
      *(float2*)(fo + t * 512 + c0) = fv;
    }
  }
}

// ---------------- combined attention-prep: ONE launch covering
//   role A (bx<16):  scores = q @ k^T / sqrt(d) -> bf16 pb (tri-skip)
//   role B (bx>=16): VWo^T = (v @ Wo)^T -> vwt (transposed store)
// Both are K=512 GEMMs sharing the verified 3-buffer ring; VWo blocks backfill
// the CUs left idle by score's upper-triangle skip. XCD-chunked remap (320%8==0).
__global__ __launch_bounds__(256) void attn_prep_kernel(
    const __bf16* __restrict__ qbuf, const __bf16* __restrict__ kbuf,
    const __bf16* __restrict__ vbuf, const __bf16* __restrict__ Wo_t,
    __bf16* __restrict__ pb, __bf16* __restrict__ vwt) {
  int bx, by;
  {
    const int cpx = (20 * 16) >> 3;
    const int lin = (int)(blockIdx.y * 20 + blockIdx.x);
    const int nl = (lin & 7) * cpx + (lin >> 3);   // bijective chunked remap
    by = nl / 20; bx = nl - by * 20;
  }
  const int z = blockIdx.z;
  const int m0 = by * 128;
  const bool isScore = bx < 16;
  const int n0 = (isScore ? bx : bx - 16) * 128;
  if (isScore && n0 > m0 + 127) return;
  const __bf16* A  = (isScore ? qbuf : vbuf) + (size_t)z * SS * DD;
  const __bf16* Bt = isScore ? (kbuf + (size_t)z * SS * DD) : Wo_t;
  constexpr int K = DD;   // 512 for both roles

  __shared__ __align__(16) __bf16 As[3 * 128 * 32];
  __shared__ __align__(16) __bf16 Bs[3 * 128 * 32];
  const int tid = threadIdx.x, lane = tid & 63, wave = tid >> 6;
  const int l15 = lane & 15, g = lane >> 4;
  const int wr = wave >> 1, wc = wave & 1;

  const int srow0 = wave * 32 + (lane >> 2);
  const int srow1 = srow0 + 16;
  const int sc0 = (((lane & 3) ^ ((srow0 >> 1) & 3)) << 4);
  const int sc1 = (((lane & 3) ^ ((srow1 >> 1) & 3)) << 4);
  const char* ga0 = (const char*)(A + (size_t)(m0 + srow0) * K) + sc0;
  const char* ga1 = (const char*)(A + (size_t)(m0 + srow1) * K) + sc1;
  const char* gb0 = (const char*)(Bt + (size_t)(n0 + srow0) * K) + sc0;
  const char* gb1 = (const char*)(Bt + (size_t)(n0 + srow1) * K) + sc1;

  const int plo = (g >> 1) ^ ((l15 >> 1) & 3);
  const int aof0 = (wr * 64 + l15) * 64 + plo * 16 + (g & 1) * 8;
  const int bof0 = (wc * 64 + l15) * 64 + plo * 16 + (g & 1) * 8;

  f32x4_t acc[4][4];
#pragma unroll
  for (int i = 0; i < 4; i++)
#pragma unroll
    for (int j = 0; j < 4; j++) acc[i][j] = (f32x4_t){0.f, 0.f, 0.f, 0.f};

  auto STAGE = [&](const int buf, const int k0) {
    const size_t kb = (size_t)k0 * 2;
    char* la = (char*)As + buf * 8192 + wave * 2048;
    char* lb = (char*)Bs + buf * 8192 + wave * 2048;
    gld16(ga0 + kb, la);
    gld16(ga1 + kb, la + 1024);
    gld16(gb0 + kb, lb);
    gld16(gb1 + kb, lb + 1024);
  };
  auto COMPUTE = [&](const int buf) {
    const char* AsB = (const char*)As + buf * 8192;
    const char* BsB = (const char*)Bs + buf * 8192;
    bf16x8_t af[4], bfr[4];
#pragma unroll
    for (int i = 0; i < 4; i++) {
      const int ao = aof0 + i * 1024;
      af[i] = mk_frag(*(const bf16x4_t*)(AsB + ao),
                      *(const bf16x4_t*)(AsB + (ao ^ 32)));
      const int bo = bof0 + i * 1024;
      bfr[i] = mk_frag(*(const bf16x4_t*)(BsB + bo),
                       *(const bf16x4_t*)(BsB + (bo ^ 32)));
    }
#pragma unroll
    for (int i = 0; i < 4; i++)
#pragma unroll
      for (int j = 0; j < 4; j++)
        acc[i][j] = __builtin_amdgcn_mfma_f32_16x16x32_bf16(af[i], bfr[j], acc[i][j], 0, 0, 0);
  };

  const int nt = K >> 5;    // 16
  STAGE(0, 0);
  STAGE(1, 32);
  STAGE(2, 64);
  int cur = 0;
  for (int t = 0; t < nt; ++t) {
    const int rem = nt - 1 - t;
    if (rem >= 2)      asm volatile("s_waitcnt vmcnt(8)" ::: "memory");
    else if (rem == 1) asm volatile("s_waitcnt vmcnt(4)" ::: "memory");
    else               asm volatile("s_waitcnt vmcnt(0)" ::: "memory");
    __builtin_amdgcn_s_barrier();
    COMPUTE(cur);
    __builtin_amdgcn_s_barrier();
    if (t + 3 < nt) STAGE(cur, (t + 3) << 5);
    cur = (cur == 2) ? 0 : cur + 1;
  }

#pragma unroll
  for (int i = 0; i < 4; i++) {
#pragma unroll
    for (int j = 0; j < 4; j++) {
      const int col = n0 + wc * 64 + j * 16 + l15;
      if (isScore) {
#pragma unroll
        for (int r = 0; r < 4; r++) {
          const int row = m0 + wr * 64 + i * 16 + g * 4 + r;
          pb[(size_t)z * SS * SS + (size_t)row * SS + col] =
              (__bf16)(acc[i][j][r] * INVSQD);
        }
      } else {
        const int row0 = m0 + wr * 64 + i * 16 + g * 4;
        bf16x4_t tv;
#pragma unroll
        for (int r = 0; r < 4; r++) tv[r] = (__bf16)acc[i][j][r];
        *(bf16x4_t*)(vwt + (size_t)z * SS * DD + (size_t)col * SS + row0) = tv;
      }
    }
  }
}

// ---------------- 128x128-tile MFMA GEMM, 3-buffer ring + counted vmcnt (T4).
// CAUSAL: k-loop ends at m0+128 (PV).  RELU: relu(acc+bias).  RES: += Res.
// PAIR (with CAUSAL): block handles m-blocks blockIdx.y and 2*gridDim.y-1-y.
// XCDS: bijective XCD-chunked remap of (x,y) (requires gridDim.x*gridDim.y%8==0).
template <bool CAUSAL, bool RELU, bool RES, bool PAIR, bool XCDS>
__global__ __launch_bounds__(256) void gemm128(
    const __bf16* __restrict__ A, const __bf16* __restrict__ Bt,
    const float* __restrict__ bias, const __bf16* __restrict__ Res,
    __bf16* __restrict__ Cb,
    int N, int K, size_t aBatch, size_t bBatch, size_t cBatch) {
  int bx = blockIdx.x, by = blockIdx.y;
  if (XCDS) {
    const int nwg = (int)(gridDim.x * gridDim.y);
    const int cpx = nwg >> 3;
    const int lin = (int)(blockIdx.y * gridDim.x + blockIdx.x);
    const int nl = (lin & 7) * cpx + (lin >> 3);
    by = nl / (int)gridDim.x;
    bx = nl - by * (int)gridDim.x;
  }
  const int n0 = bx * 128;
  __shared__ __align__(16) __bf16 As[3 * 128 * 32];   // 3 x 8 KB
  __shared__ __align__(16) __bf16 Bs[3 * 128 * 32];
  const int tid = threadIdx.x, lane = tid & 63, wave = tid >> 6;
  const int l15 = lane & 15, g = lane >> 4;
  const int wr = wave >> 1, wc = wave & 1;

  const int srow0 = wave * 32 + (lane >> 2);
  const int srow1 = srow0 + 16;
  const int sc0 = (((lane & 3) ^ ((srow0 >> 1) & 3)) << 4);
  const int sc1 = (((lane & 3) ^ ((srow1 >> 1) & 3)) << 4);
  const size_t aOff = (size_t)blockIdx.z * aBatch;
  const size_t bOff = (size_t)blockIdx.z * bBatch;
  const size_t cOff = (size_t)blockIdx.z * cBatch;
  const char* gb0 = (const char*)(Bt + bOff + (size_t)(n0 + srow0) * K) + sc0;
  const char* gb1 = (const char*)(Bt + bOff + (size_t)(n0 + srow1) * K) + sc1;

  const int plo = (g >> 1) ^ ((l15 >> 1) & 3);
  const int aof0 = (wr * 64 + l15) * 64 + plo * 16 + (g & 1) * 8;
  const int bof0 = (wc * 64 + l15) * 64 + plo * 16 + (g & 1) * 8;

  const int nhalf = PAIR ? 2 : 1;
#pragma unroll
  for (int half = 0; half < nhalf; ++half) {
    const int mb = (half == 0) ? by : (2 * (int)gridDim.y - 1 - by);
    const int m0 = mb * 128;
    const char* ga0 = (const char*)(A + aOff + (size_t)(m0 + srow0) * K) + sc0;
    const char* ga1 = (const char*)(A + aOff + (size_t)(m0 + srow1) * K) + sc1;

    f32x4_t acc[4][4];
#pragma unroll
    for (int i = 0; i < 4; i++)
#pragma unroll
      for (int j = 0; j < 4; j++) acc[i][j] = (f32x4_t){0.f, 0.f, 0.f, 0.f};

    auto STAGE = [&](const int buf, const int k0) {
      const size_t kb = (size_t)k0 * 2;
      char* la = (char*)As + buf * 8192 + wave * 2048;
      char* lb = (char*)Bs + buf * 8192 + wave * 2048;
      gld16(ga0 + kb, la);
      gld16(ga1 + kb, la + 1024);
      gld16(gb0 + kb, lb);
      gld16(gb1 + kb, lb + 1024);
    };
    auto COMPUTE = [&](const int buf) {
      const char* AsB = (const char*)As + buf * 8192;
      const char* BsB = (const char*)Bs + buf * 8192;
      bf16x8_t af[4], bfr[4];
#pragma unroll
      for (int i = 0; i < 4; i++) {
        const int ao = aof0 + i * 1024;
        af[i] = mk_frag(*(const bf16x4_t*)(AsB + ao),
                        *(const bf16x4_t*)(AsB + (ao ^ 32)));
        const int bo = bof0 + i * 1024;
        bfr[i] = mk_frag(*(const bf16x4_t*)(BsB + bo),
                         *(const bf16x4_t*)(BsB + (bo ^ 32)));
      }
#pragma unroll
      for (int i = 0; i < 4; i++)
#pragma unroll
        for (int j = 0; j < 4; j++)
          acc[i][j] = __builtin_amdgcn_mfma_f32_16x16x32_bf16(af[i], bfr[j], acc[i][j], 0, 0, 0);
    };

    const int kend = CAUSAL ? (m0 + 128) : K;
    const int nt = kend >> 5;           // >= 4 at every call site
    STAGE(0, 0);
    STAGE(1, 32);
    STAGE(2, 64);
    int cur = 0;
    for (int t = 0; t < nt; ++t) {
      const int rem = nt - 1 - t;
      if (rem >= 2)      asm volatile("s_waitcnt vmcnt(8)" ::: "memory");
      else if (rem == 1) asm volatile("s_waitcnt vmcnt(4)" ::: "memory");
      else               asm volatile("s_waitcnt vmcnt(0)" ::: "memory");
      __builtin_amdgcn_s_barrier();     // tile t visible everywhere
      COMPUTE(cur);
      __builtin_amdgcn_s_barrier();     // all reads of buf `cur` done
      if (t + 3 < nt) STAGE(cur, (t + 3) << 5);
      cur = (cur == 2) ? 0 : cur + 1;
    }

#pragma unroll
    for (int i = 0; i < 4; i++) {
#pragma unroll
      for (int j = 0; j < 4; j++) {
        const int col = n0 + wc * 64 + j * 16 + l15;
        const float bv = bias ? bias[col] : 0.f;
#pragma unroll
        for (int r = 0; r < 4; r++) {
          const int row = m0 + wr * 64 + i * 16 + g * 4 + r;
          float v = acc[i][j][r] + bv;
          if (RELU) v = fmaxf(v, 0.f);
          if (RES) v += (float)Res[cOff + (size_t)row * N + col];
          Cb[cOff + (size_t)row * N + col] = (__bf16)v;
        }
      }
    }
  }
}

// ---------------- row softmax: reads bf16 scores from pb (lower-tri valid),
// writes fp32 probs to att (full row, exact zeros above diag) + bf16 probs
// back into pb in place (only chunks PV will read). One wave per row.
__global__ __launch_bounds__(256) void softmax_kernel(
    float* __restrict__ att, __bf16* __restrict__ pb) {
  const int t = blockIdx.x * 4 + (threadIdx.x >> 6);   // global row (b*2048+q)
  const int gq = t & (SS - 1);                         // query index in batch
  const int lane = threadIdx.x & 63;
  float* row = att + (size_t)t * SS;
  __bf16* prow = pb + (size_t)t * SS;
  const int nch = (gq >> 9) + 1;   // 512-wide chunks containing valid cols
  const int wlim = ((gq & ~127) + 128 + 511) >> 9;
  float x[32];
  float m = -1e30f;
#pragma unroll
  for (int ch = 0; ch < 4; ch++) {
    float* xp = &x[ch * 8];
    if (ch < nch) {
      const int c0 = ch * 512 + lane * 8;
      bf16x8_t v = *(const bf16x8_t*)(prow + c0);
#pragma unroll
      for (int j = 0; j < 8; j++) {
        const float f = (float)v[j];
        xp[j] = (c0 + j <= gq) ? f : -1e30f;  // select: immune to garbage
        m = fmaxf(m, xp[j]);
      }
    } else {
#pragma unroll
      for (int j = 0; j < 8; j++) xp[j] = -1e30f;
    }
  }
#pragma unroll
  for (int off = 1; off < 64; off <<= 1) m = fmaxf(m, __shfl_xor(m, off, 64));
  float s = 0.f;
#pragma unroll
  for (int i = 0; i < 32; i++) { x[i] = __expf(x[i] - m); s += x[i]; }
#pragma unroll
  for (int off = 1; off < 64; off <<= 1) s += __shfl_xor(s, off, 64);
  const float inv = 1.f / s;
#pragma unroll
  for (int ch = 0; ch < 4; ch++) {
    const int c0 = ch * 512 + lane * 8;
    float o[8];
    bf16x8_t ov;
#pragma unroll
    for (int j = 0; j < 8; j++) {
      const float pv = x[ch * 8 + j] * inv;  // masked entries exactly 0
      o[j] = pv;
      ov[j] = (__bf16)pv;
    }
    float4 f0, f1;
    f0.x = o[0]; f0.y = o[1]; f0.z = o[2]; f0.w = o[3];
    f1.x = o[4]; f1.y = o[5]; f1.z = o[6]; f1.w = o[7];
    *(float4*)(row + c0) = f0;
    *(float4*)(row + c0 + 4) = f1;
    if (ch < wlim) *(bf16x8_t*)(prow + c0) = ov;
  }
}

// ---------------- LayerNorm over D=512 (population var, eps inside sqrt)
__global__ __launch_bounds__(256) void ln_kernel(
    const __bf16* __restrict__ X, const float* __restrict__ gam,
    const float* __restrict__ bet, __bf16* __restrict__ Ob) {
  const int t = blockIdx.x * 4 + (threadIdx.x >> 6);
  const int lane = threadIdx.x & 63;
  const int d0 = lane * 8;
  bf16x8_t xv = *(const bf16x8_t*)(X + (size_t)t * DD + d0);
  float x[8];
#pragma unroll
  for (int j = 0; j < 8; j++) x[j] = (float)xv[j];
  float s = 0.f, sq = 0.f;
#pragma unroll
  for (int j = 0; j < 8; j++) { s += x[j]; sq += x[j] * x[j]; }
#pragma unroll
  for (int off = 1; off < 64; off <<= 1) {
    s += __shfl_xor(s, off, 64);
    sq += __shfl_xor(sq, off, 64);
  }
  const float mean = s * (1.f / 512.f);
  const float var = sq * (1.f / 512.f) - mean * mean;
  const float rstd = rsqrtf(var + 1e-6f);
  float4 g0 = *(const float4*)(gam + d0), g1v = *(const float4*)(gam + d0 + 4);
  float4 b0 = *(const float4*)(bet + d0), b1v = *(const float4*)(bet + d0 + 4);
  float gg[8] = {g0.x, g0.y, g0.z, g0.w, g1v.x, g1v.y, g1v.z, g1v.w};
  float bb2[8] = {b0.x, b0.y, b0.z, b0.w, b1v.x, b1v.y, b1v.z, b1v.w};
  bf16x8_t ov;
#pragma unroll
  for (int j = 0; j < 8; j++)
    ov[j] = (__bf16)((x[j] - mean) * rstd * gg[j] + bb2[j]);
  *(bf16x8_t*)(Ob + (size_t)t * DD + d0) = ov;
}

// ---------------- fused LN2 + final projection:
// r = LN(X) -> o_r (fp32) AND pred = r @ Wfin + bfin -> P1,P2 (no o_r re-read)
__global__ __launch_bounds__(256) void ln_final_kernel(
    const __bf16* __restrict__ X, const float* __restrict__ gam,
    const float* __restrict__ bet, float* __restrict__ Of,
    const float* __restrict__ Wfin, const float* __restrict__ bfin,
    float* __restrict__ P1, float* __restrict__ P2) {
  __shared__ float wfs[512][16];
  __shared__ float rf[4][516];           // +4 pad: de-bank the k-column reads
  for (int i = threadIdx.x; i < 512 * 16; i += 256) wfs[i >> 4][i & 15] = Wfin[i];
  const int tw = threadIdx.x >> 6;       // token slot within block
  const int t = blockIdx.x * 4 + tw;
  const int lane = threadIdx.x & 63;
  const int d0 = lane * 8;
  bf16x8_t xv = *(const bf16x8_t*)(X + (size_t)t * DD + d0);
  float x[8];
#pragma unroll
  for (int j = 0; j < 8; j++) x[j] = (float)xv[j];
  float s = 0.f, sq = 0.f;
#pragma unroll
  for (int j = 0; j < 8; j++) { s += x[j]; sq += x[j] * x[j]; }
#pragma unroll
  for (int off = 1; off < 64; off <<= 1) {
    s += __shfl_xor(s, off, 64);
    sq += __shfl_xor(sq, off, 64);
  }
  const float mean = s * (1.f / 512.f);
  const float var = sq * (1.f / 512.f) - mean * mean;
  const float rstd = rsqrtf(var + 1e-6f);
  float4 g0 = *(const float4*)(gam + d0), g1v = *(const float4*)(gam + d0 + 4);
  float4 b0 = *(const float4*)(bet + d0), b1v = *(const float4*)(bet + d0 + 4);
  float gg[8] = {g0.x, g0.y, g0.z, g0.w, g1v.x, g1v.y, g1v.z, g1v.w};
  float bb2[8] = {b0.x, b0.y, b0.z, b0.w, b1v.x, b1v.y, b1v.z, b1v.w};
  float o[8];
  float4 f0, f1;
#pragma unroll
  for (int j = 0; j < 8; j++) {
    o[j] = (x[j] - mean) * rstd * gg[j] + bb2[j];
    rf[tw][d0 + j] = o[j];
  }
  f0.x = o[0]; f0.y = o[1]; f0.z = o[2]; f0.w = o[3];
  f1.x = o[4]; f1.y = o[5]; f1.z = o[6]; f1.w = o[7];
  *(float4*)(Of + (size_t)t * DD + d0) = f0;
  *(float4*)(Of + (size_t)t * DD + d0 + 4) = f1;
  __syncthreads();
  if (threadIdx.x < 64) {
    const int tt = threadIdx.x >> 4, n = threadIdx.x & 15;
    float acc = 0.f;
#pragma unroll 4
    for (int k = 0; k < 512; k += 4) {
      const float4 rv = *(const float4*)&rf[tt][k];
      acc += rv.x * wfs[k][n] + rv.y * wfs[k + 1][n] +
             rv.z * wfs[k + 2][n] + rv.w * wfs[k + 3][n];
    }
    const float v = acc + bfin[n];
    const size_t tok = (size_t)blockIdx.x * 4 + tt;
    P1[tok * 16 + n] = v;
    P2[tok * 16 + n] = v;
  }
}

extern "C" void kernel_launch(void* const* d_in, const int* in_sizes, int n_in,
                              void* d_out, int out_size, void* d_ws, size_t ws_size,
                              hipStream_t stream) {
  const float* inp  = (const float*)d_in[0];
  const float* Wp   = (const float*)d_in[2];
  const float* bp   = (const float*)d_in[3];
  const float* Wq   = (const float*)d_in[4];
  const float* bq   = (const float*)d_in[5];
  const float* Wk   = (const float*)d_in[6];
  const float* bk   = (const float*)d_in[7];
  const float* Wv   = (const float*)d_in[8];
  const float* bv   = (const float*)d_in[9];
  const float* Wo   = (const float*)d_in[10];
  const float* bo   = (const float*)d_in[11];
  const float* g1   = (const float*)d_in[12];
  const float* be1  = (const float*)d_in[13];
  const float* g2   = (const float*)d_in[14];
  const float* be2  = (const float*)d_in[15];
  const float* Wf1  = (const float*)d_in[16];
  const float* bf1  = (const float*)d_in[17];
  const float* Wf2  = (const float*)d_in[18];
  const float* bf2  = (const float*)d_in[19];
  const float* Wfin = (const float*)d_in[20];
  const float* bfin = (const float*)d_in[21];
  (void)in_sizes; (void)n_in; (void)out_size; (void)ws_size;

  float* out = (float*)d_out;
  float* o_pred1 = out;                    // (B,P,S,16)
  float* o_pred2 = out + 262144;
  float* o_k     = out + 524288;           // (B,P,S,512)
  float* o_v     = out + 8912896;
  float* o_r     = out + 17301504;
  float* o_att   = out + 25690112;         // (B,P,S,S)

  // workspace carve-up (~170 MB)
  char* base = (char*)d_ws;
  size_t off = 0;
  auto takeB = [&](size_t bytes) -> char* {
    char* p = base + off;
    off += (bytes + 255) & ~(size_t)255;
    return p;
  };
  float*  Wfold = (float*)takeB((size_t)16 * 1536 * 4);
  float*  bfold = (float*)takeB((size_t)1536 * 4);
  __bf16* Wo_t  = (__bf16*)takeB((size_t)DD * DD * 2);
  __bf16* Wf1_t = (__bf16*)takeB((size_t)DD * DFFX * 2);
  __bf16* Wf2_t = (__bf16*)takeB((size_t)DD * DFFX * 2);
  __bf16* xb    = (__bf16*)takeB((size_t)TT * DD * 2);
  __bf16* qbuf  = (__bf16*)takeB((size_t)TT * DD * 2);
  __bf16* kbuf  = (__bf16*)takeB((size_t)TT * DD * 2);
  __bf16* vbuf  = (__bf16*)takeB((size_t)TT * DD * 2);
  __bf16* vwt   = (__bf16*)takeB((size_t)TT * DD * 2);   // V@Wo transposed [z][D][S]
  __bf16* h1b   = (__bf16*)takeB((size_t)TT * DD * 2);
  __bf16* lninb = (__bf16*)takeB((size_t)TT * DD * 2);
  __bf16* ffb   = (__bf16*)takeB((size_t)TT * DFFX * 2);
  __bf16* pb    = ffb;  // bf16 scores->probs alias FFN scratch (same element
                        // count; pb dead before FFN1 writes ffb)

  // weights -> bf16 transposed [N][K], one merged launch
  transpose_conv3<<<dim3(2304), 256, 0, stream>>>(Wo, Wf1, Wf2, Wo_t, Wf1_t, Wf2_t);

  // fold Wp into Wq/Wk/Wv:  q|k|v = inp @ Wfold + bfold  (K=16)
  fold_kernel<<<dim3(96), 256, 0, stream>>>(Wp, bp, Wq, bq, Wk, bk, Wv, bv,
                                            Wfold, bfold);

  // q,k,v (+ fp32 o_k/o_v) and x residual, one K=16 launch (4 slices)
  smallk_kernel<<<dim3(TT / 16, 4), 256, 0, stream>>>(
      inp, Wfold, bfold, Wp, bp, qbuf, kbuf, vbuf, xb, o_k, o_v);

  // combined: scores -> bf16 pb (tri) AND VWo^T -> vwt, one launch
  attn_prep_kernel<<<dim3(20, 16, BB), 256, 0, stream>>>(
      qbuf, kbuf, vbuf, Wo_t, pb, vwt);

  // softmax: bf16 scores (pb) -> fp32 probs (o_att, zeros above diag) + bf16 pb
  softmax_kernel<<<dim3(TT / 4), 256, 0, stream>>>(o_att, pb);

  // PV' = P @ VWo + bo + x -> LN1 input (causal k-tile skip, PAIR balance)
  gemm128<true, false, true, true, false><<<dim3(4, 8, BB), 256, 0, stream>>>(
      pb, vwt, bo, xb, lninb, DD, SS,
      (size_t)SS * SS, (size_t)DD * SS, (size_t)SS * DD);

  // LN1
  ln_kernel<<<dim3(TT / 4), 256, 0, stream>>>(lninb, g1, be1, h1b);

  // FFN with XCD-chunked block swizzle (A-panel L2 reuse within XCD)
  gemm128<false, true, false, false, true><<<dim3(16, 128, 1), 256, 0, stream>>>(
      h1b, Wf1_t, bf1, nullptr, ffb, DFFX, DD, 0, 0, 0);
  gemm128<false, false, true, false, true><<<dim3(4, 128, 1), 256, 0, stream>>>(
      ffb, Wf2_t, bf2, h1b, lninb, DD, DFFX, 0, 0, 0);

  // fused LN2 -> r (fp32 output) + final projection -> pred (both slots)
  ln_final_kernel<<<dim3(TT / 4), 256, 0, stream>>>(
      lninb, g2, be2, o_r, Wfin, bfin, o_pred1, o_pred2);
}

// Round 12
// 435.694 us; speedup vs baseline: 1.3042x; 1.0021x over previous
//
#include <hip/hip_runtime.h>
#include <hip/hip_bf16.h>
#include <stdint.h>

// Problem dims (SMC transformer, noise=False => causal self-attention)
#define BB 8
#define SS 2048
#define TT (BB*SS)       // 16384 tokens total (P=1)
#define DD 512
#define DFFX 2048

static __device__ const float SQRTD  = 22.627416997969522f;   // sqrt(512)
static __device__ const float INVSQD = 0.04419417382415922f;  // 1/sqrt(512)

typedef __attribute__((ext_vector_type(4))) float  f32x4_t;
typedef __attribute__((ext_vector_type(8))) __bf16 bf16x8_t;
typedef __attribute__((ext_vector_type(4))) __bf16 bf16x4_t;
typedef __attribute__((ext_vector_type(2))) __bf16 bf16x2_t;

// MFMA 16x16x32 bf16 operand layout (gfx950), HW-verified rounds 1-11:
//   A: lane l, elem e -> A[l&15][4*(l>>4) + (e&3) + 16*(e>>2)]
//   B: lane l, elem e -> B[4*(l>>4) + (e&3) + 16*(e>>2)][l&15]
//   D: lane l, reg  r -> D[4*(l>>4) + r][l&15]
static __device__ __forceinline__ bf16x8_t mk_frag(bf16x4_t lo, bf16x4_t hi) {
  return __builtin_shufflevector(lo, hi, 0, 1, 2, 3, 4, 5, 6, 7);
}

// async global->LDS, 16B per lane, dest = uniform base + lane*16
typedef __attribute__((address_space(1))) const unsigned int g_u32;
typedef __attribute__((address_space(3))) unsigned int lds_u32;
static __device__ __forceinline__ void gld16(const void* g, void* l) {
  __builtin_amdgcn_global_load_lds((g_u32*)g, (lds_u32*)l, 16, 0, 0);
}

// ---------------- merged weight transpose+convert for Wo/Wf1/Wf2:
// dst[C][R] (bf16) = src[R][C] (f32); 2304 blocks, segment decoded from bx.
__global__ __launch_bounds__(256) void transpose_conv3(
    const float* __restrict__ Wo, const float* __restrict__ Wf1,
    const float* __restrict__ Wf2, __bf16* __restrict__ Wo_t,
    __bf16* __restrict__ Wf1_t, __bf16* __restrict__ Wf2_t) {
  const int bx = blockIdx.x;
  const float* src; __bf16* dst; int C, R, gx, gy;
  if (bx < 256)       { src = Wo;  dst = Wo_t;  R = 512;  C = 512;  gx = bx & 15;  gy = bx >> 4; }
  else if (bx < 1280) { const int b = bx - 256;  src = Wf1; dst = Wf1_t; R = 512;  C = 2048; gx = b & 63; gy = b >> 6; }
  else                { const int b = bx - 1280; src = Wf2; dst = Wf2_t; R = 2048; C = 512;  gx = b & 15; gy = b >> 4; }
  __shared__ float tile[32][33];
  const int c0 = gx * 32, r0 = gy * 32;
  const int tx = threadIdx.x & 31, ty = threadIdx.x >> 5;
#pragma unroll
  for (int i = 0; i < 4; i++)
    tile[ty + 8*i][tx] = src[(size_t)(r0 + ty + 8*i) * C + c0 + tx];
  __syncthreads();
#pragma unroll
  for (int i = 0; i < 4; i++)
    dst[(size_t)(c0 + ty + 8*i) * R + r0 + tx] = (__bf16)tile[tx][ty + 8*i];
}

// ---------------- fold: Wfold[r][c] = sqrt(d) * (Wp @ W{q,k,v})[r][c]  (16x1536)
//                  bfold[c] = sqrt(d) * (bp @ W)[c] + b[c]
__global__ __launch_bounds__(256) void fold_kernel(
    const float* __restrict__ Wp, const float* __restrict__ bp,
    const float* __restrict__ Wq, const float* __restrict__ bq,
    const float* __restrict__ Wk, const float* __restrict__ bk,
    const float* __restrict__ Wv, const float* __restrict__ bv,
    float* __restrict__ Wfold, float* __restrict__ bfold) {
  __shared__ float wp[16][512];
  __shared__ float bps[512];
  for (int i = threadIdx.x; i < 16 * 512; i += 256) wp[i >> 9][i & 511] = Wp[i];
  for (int i = threadIdx.x; i < 512; i += 256) bps[i] = bp[i];
  __syncthreads();
  const int cl = threadIdx.x & 15, r = threadIdx.x >> 4;
  const int cg = blockIdx.x * 16 + cl;           // 0..1535
  const int sub = cg >> 9, wc = cg & 511;        // uniform per block
  const float* W = sub == 0 ? Wq : sub == 1 ? Wk : Wv;
  const float* bb = sub == 0 ? bq : sub == 1 ? bk : bv;
  float acc = 0.f, bacc = 0.f;
  for (int k = 0; k < 512; k += 4) {
    const float4 wpv = *(const float4*)&wp[r][k];
    const float g0 = W[(size_t)k * 512 + wc];
    const float g1 = W[(size_t)(k + 1) * 512 + wc];
    const float g2 = W[(size_t)(k + 2) * 512 + wc];
    const float g3 = W[(size_t)(k + 3) * 512 + wc];
    acc += wpv.x * g0 + wpv.y * g1 + wpv.z * g2 + wpv.w * g3;
    if (r == 0) {
      const float4 b4 = *(const float4*)&bps[k];
      bacc += b4.x * g0 + b4.y * g1 + b4.z * g2 + b4.w * g3;
    }
  }
  Wfold[(size_t)r * 1536 + cg] = acc * SQRTD;
  if (r == 0) bfold[cg] = bacc * SQRTD + bb[wc];
}

// ---------------- small-K (K=16) dense, 4 slices: sl 0/1/2 = q/k/v via Wfold
// (ldw=1536), sl 3 = x via Wp (ldw=512, scale=sqrt(d)). 16 tokens/block;
// thread owns 2 cols with the 16x2 weight block in VGPRs.
__global__ __launch_bounds__(256) void smallk_kernel(
    const float* __restrict__ inp,
    const float* __restrict__ Wfold, const float* __restrict__ bfold,
    const float* __restrict__ Wp, const float* __restrict__ bp,
    __bf16* __restrict__ qb, __bf16* __restrict__ kb, __bf16* __restrict__ vb,
    __bf16* __restrict__ xb, float* __restrict__ o_k, float* __restrict__ o_v) {
  const int sl = blockIdx.y;
  const float* W; const float* bias; int ldw; float scale;
  __bf16* ob; float* fo;
  if (sl == 3) { W = Wp; bias = bp; ldw = 512; scale = SQRTD; ob = xb; fo = nullptr; }
  else {
    W = Wfold + sl * 512; bias = bfold + sl * 512; ldw = 1536; scale = 1.f;
    ob = sl == 0 ? qb : sl == 1 ? kb : vb;
    fo = sl == 0 ? (float*)nullptr : sl == 1 ? o_k : o_v;
  }
  __shared__ float ivl[16][16];
  const int tid = threadIdx.x;
  ivl[tid >> 4][tid & 15] = inp[(size_t)blockIdx.x * 256 + tid];
  const int c0 = 2 * tid;
  float w0[16], w1[16];
#pragma unroll
  for (int r = 0; r < 16; r++) {
    w0[r] = W[(size_t)r * ldw + c0];
    w1[r] = W[(size_t)r * ldw + c0 + 1];
  }
  const float bb0 = bias[c0], bb1 = bias[c0 + 1];
  __syncthreads();
#pragma unroll 4
  for (int tt = 0; tt < 16; ++tt) {
    const float4 i0 = *(const float4*)&ivl[tt][0];
    const float4 i1 = *(const float4*)&ivl[tt][4];
    const float4 i2 = *(const float4*)&ivl[tt][8];
    const float4 i3 = *(const float4*)&ivl[tt][12];
    float a0, a1;
    a0  = i0.x * w0[0];   a1  = i0.x * w1[0];
    a0 += i0.y * w0[1];   a1 += i0.y * w1[1];
    a0 += i0.z * w0[2];   a1 += i0.z * w1[2];
    a0 += i0.w * w0[3];   a1 += i0.w * w1[3];
    a0 += i1.x * w0[4];   a1 += i1.x * w1[4];
    a0 += i1.y * w0[5];   a1 += i1.y * w1[5];
    a0 += i1.z * w0[6];   a1 += i1.z * w1[6];
    a0 += i1.w * w0[7];   a1 += i1.w * w1[7];
    a0 += i2.x * w0[8];   a1 += i2.x * w1[8];
    a0 += i2.y * w0[9];   a1 += i2.y * w1[9];
    a0 += i2.z * w0[10];  a1 += i2.z * w1[10];
    a0 += i2.w * w0[11];  a1 += i2.w * w1[11];
    a0 += i3.x * w0[12];  a1 += i3.x * w1[12];
    a0 += i3.y * w0[13];  a1 += i3.y * w1[13];
    a0 += i3.z * w0[14];  a1 += i3.z * w1[14];
    a0 += i3.w * w0[15];  a1 += i3.w * w1[15];
    const float v0 = (a0 + bb0) * scale;
    const float v1 = (a1 + bb1) * scale;
    const size_t t = (size_t)blockIdx.x * 16 + tt;
    bf16x2_t pv; pv[0] = (__bf16)v0; pv[1] = (__bf16)v1;
    *(bf16x2_t*)(ob + t * 512 + c0) = pv;
    if (fo) {
      float2 fv; fv.x = v0; fv.y = v1;
      *(float2*)(fo + t * 512 + c0) = fv;
    }
  }
}

// ---------------- combined attention-prep: ONE launch covering
//   role A (bx<16):  scores = q @ k^T / sqrt(d) -> bf16 pb (tri-skip)
//   role B (bx>=16): VWo^T = (v @ Wo)^T -> vwt (transposed store)
// Both are K=512 GEMMs sharing the verified 3-buffer ring; VWo blocks backfill
// the CUs left idle by score's upper-triangle skip. XCD-chunked remap (320%8==0).
__global__ __launch_bounds__(256) void attn_prep_kernel(
    const __bf16* __restrict__ qbuf, const __bf16* __restrict__ kbuf,
    const __bf16* __restrict__ vbuf, const __bf16* __restrict__ Wo_t,
    __bf16* __restrict__ pb, __bf16* __restrict__ vwt) {
  int bx, by;
  {
    const int cpx = (20 * 16) >> 3;
    const int lin = (int)(blockIdx.y * 20 + blockIdx.x);
    const int nl = (lin & 7) * cpx + (lin >> 3);   // bijective chunked remap
    by = nl / 20; bx = nl - by * 20;
  }
  const int z = blockIdx.z;
  const int m0 = by * 128;
  const bool isScore = bx < 16;
  const int n0 = (isScore ? bx : bx - 16) * 128;
  if (isScore && n0 > m0 + 127) return;
  const __bf16* A  = (isScore ? qbuf : vbuf) + (size_t)z * SS * DD;
  const __bf16* Bt = isScore ? (kbuf + (size_t)z * SS * DD) : Wo_t;
  constexpr int K = DD;   // 512 for both roles

  __shared__ __align__(16) __bf16 As[3 * 128 * 32];
  __shared__ __align__(16) __bf16 Bs[3 * 128 * 32];
  const int tid = threadIdx.x, lane = tid & 63, wave = tid >> 6;
  const int l15 = lane & 15, g = lane >> 4;
  const int wr = wave >> 1, wc = wave & 1;

  const int srow0 = wave * 32 + (lane >> 2);
  const int srow1 = srow0 + 16;
  const int sc0 = (((lane & 3) ^ ((srow0 >> 1) & 3)) << 4);
  const int sc1 = (((lane & 3) ^ ((srow1 >> 1) & 3)) << 4);
  const char* ga0 = (const char*)(A + (size_t)(m0 + srow0) * K) + sc0;
  const char* ga1 = (const char*)(A + (size_t)(m0 + srow1) * K) + sc1;
  const char* gb0 = (const char*)(Bt + (size_t)(n0 + srow0) * K) + sc0;
  const char* gb1 = (const char*)(Bt + (size_t)(n0 + srow1) * K) + sc1;

  const int plo = (g >> 1) ^ ((l15 >> 1) & 3);
  const int aof0 = (wr * 64 + l15) * 64 + plo * 16 + (g & 1) * 8;
  const int bof0 = (wc * 64 + l15) * 64 + plo * 16 + (g & 1) * 8;

  f32x4_t acc[4][4];
#pragma unroll
  for (int i = 0; i < 4; i++)
#pragma unroll
    for (int j = 0; j < 4; j++) acc[i][j] = (f32x4_t){0.f, 0.f, 0.f, 0.f};

  auto STAGE = [&](const int buf, const int k0) {
    const size_t kb = (size_t)k0 * 2;
    char* la = (char*)As + buf * 8192 + wave * 2048;
    char* lb = (char*)Bs + buf * 8192 + wave * 2048;
    gld16(ga0 + kb, la);
    gld16(ga1 + kb, la + 1024);
    gld16(gb0 + kb, lb);
    gld16(gb1 + kb, lb + 1024);
  };
  auto COMPUTE = [&](const int buf) {
    const char* AsB = (const char*)As + buf * 8192;
    const char* BsB = (const char*)Bs + buf * 8192;
    bf16x8_t af[4], bfr[4];
#pragma unroll
    for (int i = 0; i < 4; i++) {
      const int ao = aof0 + i * 1024;
      af[i] = mk_frag(*(const bf16x4_t*)(AsB + ao),
                      *(const bf16x4_t*)(AsB + (ao ^ 32)));
      const int bo = bof0 + i * 1024;
      bfr[i] = mk_frag(*(const bf16x4_t*)(BsB + bo),
                       *(const bf16x4_t*)(BsB + (bo ^ 32)));
    }
#pragma unroll
    for (int i = 0; i < 4; i++)
#pragma unroll
      for (int j = 0; j < 4; j++)
        acc[i][j] = __builtin_amdgcn_mfma_f32_16x16x32_bf16(af[i], bfr[j], acc[i][j], 0, 0, 0);
  };

  const int nt = K >> 5;    // 16
  STAGE(0, 0);
  STAGE(1, 32);
  STAGE(2, 64);
  int cur = 0;
  for (int t = 0; t < nt; ++t) {
    const int rem = nt - 1 - t;
    if (rem >= 2)      asm volatile("s_waitcnt vmcnt(8)" ::: "memory");
    else if (rem == 1) asm volatile("s_waitcnt vmcnt(4)" ::: "memory");
    else               asm volatile("s_waitcnt vmcnt(0)" ::: "memory");
    __builtin_amdgcn_s_barrier();
    COMPUTE(cur);
    __builtin_amdgcn_s_barrier();
    if (t + 3 < nt) STAGE(cur, (t + 3) << 5);
    cur = (cur == 2) ? 0 : cur + 1;
  }

#pragma unroll
  for (int i = 0; i < 4; i++) {
#pragma unroll
    for (int j = 0; j < 4; j++) {
      const int col = n0 + wc * 64 + j * 16 + l15;
      if (isScore) {
#pragma unroll
        for (int r = 0; r < 4; r++) {
          const int row = m0 + wr * 64 + i * 16 + g * 4 + r;
          pb[(size_t)z * SS * SS + (size_t)row * SS + col] =
              (__bf16)(acc[i][j][r] * INVSQD);
        }
      } else {
        const int row0 = m0 + wr * 64 + i * 16 + g * 4;
        bf16x4_t tv;
#pragma unroll
        for (int r = 0; r < 4; r++) tv[r] = (__bf16)acc[i][j][r];
        *(bf16x4_t*)(vwt + (size_t)z * SS * DD + (size_t)col * SS + row0) = tv;
      }
    }
  }
}

// ---------------- 128x128-tile MFMA GEMM, 3-buffer ring + counted vmcnt (T4).
// CAUSAL: k-loop ends at m0+128 (PV).  RELU: relu(acc+bias).  RES: += Res.
// XCDS: bijective XCD-chunked remap of (x,y) (requires gridDim.x*gridDim.y%8==0).
// (PAIR removed after R12 audit: 256-block PAIR = 1 wave/SIMD, worse than
//  512-block greedy with 2 blocks/CU — scheduler smooths causal imbalance.)
template <bool CAUSAL, bool RELU, bool RES, bool XCDS>
__global__ __launch_bounds__(256) void gemm128(
    const __bf16* __restrict__ A, const __bf16* __restrict__ Bt,
    const float* __restrict__ bias, const __bf16* __restrict__ Res,
    __bf16* __restrict__ Cb,
    int N, int K, size_t aBatch, size_t bBatch, size_t cBatch) {
  int bx = blockIdx.x, by = blockIdx.y;
  if (XCDS) {
    const int nwg = (int)(gridDim.x * gridDim.y);
    const int cpx = nwg >> 3;
    const int lin = (int)(blockIdx.y * gridDim.x + blockIdx.x);
    const int nl = (lin & 7) * cpx + (lin >> 3);
    by = nl / (int)gridDim.x;
    bx = nl - by * (int)gridDim.x;
  }
  const int n0 = bx * 128;
  const int m0 = by * 128;
  __shared__ __align__(16) __bf16 As[3 * 128 * 32];   // 3 x 8 KB
  __shared__ __align__(16) __bf16 Bs[3 * 128 * 32];
  const int tid = threadIdx.x, lane = tid & 63, wave = tid >> 6;
  const int l15 = lane & 15, g = lane >> 4;
  const int wr = wave >> 1, wc = wave & 1;

  const int srow0 = wave * 32 + (lane >> 2);
  const int srow1 = srow0 + 16;
  const int sc0 = (((lane & 3) ^ ((srow0 >> 1) & 3)) << 4);
  const int sc1 = (((lane & 3) ^ ((srow1 >> 1) & 3)) << 4);
  const size_t aOff = (size_t)blockIdx.z * aBatch;
  const size_t bOff = (size_t)blockIdx.z * bBatch;
  const size_t cOff = (size_t)blockIdx.z * cBatch;
  const char* gb0 = (const char*)(Bt + bOff + (size_t)(n0 + srow0) * K) + sc0;
  const char* gb1 = (const char*)(Bt + bOff + (size_t)(n0 + srow1) * K) + sc1;
  const char* ga0 = (const char*)(A + aOff + (size_t)(m0 + srow0) * K) + sc0;
  const char* ga1 = (const char*)(A + aOff + (size_t)(m0 + srow1) * K) + sc1;

  const int plo = (g >> 1) ^ ((l15 >> 1) & 3);
  const int aof0 = (wr * 64 + l15) * 64 + plo * 16 + (g & 1) * 8;
  const int bof0 = (wc * 64 + l15) * 64 + plo * 16 + (g & 1) * 8;

  f32x4_t acc[4][4];
#pragma unroll
  for (int i = 0; i < 4; i++)
#pragma unroll
    for (int j = 0; j < 4; j++) acc[i][j] = (f32x4_t){0.f, 0.f, 0.f, 0.f};

  auto STAGE = [&](const int buf, const int k0) {
    const size_t kb = (size_t)k0 * 2;
    char* la = (char*)As + buf * 8192 + wave * 2048;
    char* lb = (char*)Bs + buf * 8192 + wave * 2048;
    gld16(ga0 + kb, la);
    gld16(ga1 + kb, la + 1024);
    gld16(gb0 + kb, lb);
    gld16(gb1 + kb, lb + 1024);
  };
  auto COMPUTE = [&](const int buf) {
    const char* AsB = (const char*)As + buf * 8192;
    const char* BsB = (const char*)Bs + buf * 8192;
    bf16x8_t af[4], bfr[4];
#pragma unroll
    for (int i = 0; i < 4; i++) {
      const int ao = aof0 + i * 1024;
      af[i] = mk_frag(*(const bf16x4_t*)(AsB + ao),
                      *(const bf16x4_t*)(AsB + (ao ^ 32)));
      const int bo = bof0 + i * 1024;
      bfr[i] = mk_frag(*(const bf16x4_t*)(BsB + bo),
                       *(const bf16x4_t*)(BsB + (bo ^ 32)));
    }
#pragma unroll
    for (int i = 0; i < 4; i++)
#pragma unroll
      for (int j = 0; j < 4; j++)
        acc[i][j] = __builtin_amdgcn_mfma_f32_16x16x32_bf16(af[i], bfr[j], acc[i][j], 0, 0, 0);
  };

  const int kend = CAUSAL ? (m0 + 128) : K;
  const int nt = kend >> 5;           // >= 4 at every call site
  STAGE(0, 0);
  STAGE(1, 32);
  STAGE(2, 64);
  int cur = 0;
  for (int t = 0; t < nt; ++t) {
    const int rem = nt - 1 - t;
    if (rem >= 2)      asm volatile("s_waitcnt vmcnt(8)" ::: "memory");
    else if (rem == 1) asm volatile("s_waitcnt vmcnt(4)" ::: "memory");
    else               asm volatile("s_waitcnt vmcnt(0)" ::: "memory");
    __builtin_amdgcn_s_barrier();     // tile t visible everywhere
    COMPUTE(cur);
    __builtin_amdgcn_s_barrier();     // all reads of buf `cur` done
    if (t + 3 < nt) STAGE(cur, (t + 3) << 5);
    cur = (cur == 2) ? 0 : cur + 1;
  }

#pragma unroll
  for (int i = 0; i < 4; i++) {
#pragma unroll
    for (int j = 0; j < 4; j++) {
      const int col = n0 + wc * 64 + j * 16 + l15;
      const float bv = bias ? bias[col] : 0.f;
#pragma unroll
      for (int r = 0; r < 4; r++) {
        const int row = m0 + wr * 64 + i * 16 + g * 4 + r;
        float v = acc[i][j][r] + bv;
        if (RELU) v = fmaxf(v, 0.f);
        if (RES) v += (float)Res[cOff + (size_t)row * N + col];
        Cb[cOff + (size_t)row * N + col] = (__bf16)v;
      }
    }
  }
}

// ---------------- row softmax: reads bf16 scores from pb (lower-tri valid),
// writes fp32 probs to att (full row, exact zeros above diag) + bf16 probs
// back into pb in place (only chunks PV will read). One wave per row.
__global__ __launch_bounds__(256) void softmax_kernel(
    float* __restrict__ att, __bf16* __restrict__ pb) {
  const int t = blockIdx.x * 4 + (threadIdx.x >> 6);   // global row (b*2048+q)
  const int gq = t & (SS - 1);                         // query index in batch
  const int lane = threadIdx.x & 63;
  float* row = att + (size_t)t * SS;
  __bf16* prow = pb + (size_t)t * SS;
  const int nch = (gq >> 9) + 1;   // 512-wide chunks containing valid cols
  const int wlim = ((gq & ~127) + 128 + 511) >> 9;
  float x[32];
  float m = -1e30f;
#pragma unroll
  for (int ch = 0; ch < 4; ch++) {
    float* xp = &x[ch * 8];
    if (ch < nch) {
      const int c0 = ch * 512 + lane * 8;
      bf16x8_t v = *(const bf16x8_t*)(prow + c0);
#pragma unroll
      for (int j = 0; j < 8; j++) {
        const float f = (float)v[j];
        xp[j] = (c0 + j <= gq) ? f : -1e30f;  // select: immune to garbage
        m = fmaxf(m, xp[j]);
      }
    } else {
#pragma unroll
      for (int j = 0; j < 8; j++) xp[j] = -1e30f;
    }
  }
#pragma unroll
  for (int off = 1; off < 64; off <<= 1) m = fmaxf(m, __shfl_xor(m, off, 64));
  float s = 0.f;
#pragma unroll
  for (int i = 0; i < 32; i++) { x[i] = __expf(x[i] - m); s += x[i]; }
#pragma unroll
  for (int off = 1; off < 64; off <<= 1) s += __shfl_xor(s, off, 64);
  const float inv = 1.f / s;
#pragma unroll
  for (int ch = 0; ch < 4; ch++) {
    const int c0 = ch * 512 + lane * 8;
    float o[8];
    bf16x8_t ov;
#pragma unroll
    for (int j = 0; j < 8; j++) {
      const float pv = x[ch * 8 + j] * inv;  // masked entries exactly 0
      o[j] = pv;
      ov[j] = (__bf16)pv;
    }
    float4 f0, f1;
    f0.x = o[0]; f0.y = o[1]; f0.z = o[2]; f0.w = o[3];
    f1.x = o[4]; f1.y = o[5]; f1.z = o[6]; f1.w = o[7];
    *(float4*)(row + c0) = f0;
    *(float4*)(row + c0 + 4) = f1;
    if (ch < wlim) *(bf16x8_t*)(prow + c0) = ov;
  }
}

// ---------------- LayerNorm over D=512 (population var, eps inside sqrt)
__global__ __launch_bounds__(256) void ln_kernel(
    const __bf16* __restrict__ X, const float* __restrict__ gam,
    const float* __restrict__ bet, __bf16* __restrict__ Ob) {
  const int t = blockIdx.x * 4 + (threadIdx.x >> 6);
  const int lane = threadIdx.x & 63;
  const int d0 = lane * 8;
  bf16x8_t xv = *(const bf16x8_t*)(X + (size_t)t * DD + d0);
  float x[8];
#pragma unroll
  for (int j = 0; j < 8; j++) x[j] = (float)xv[j];
  float s = 0.f, sq = 0.f;
#pragma unroll
  for (int j = 0; j < 8; j++) { s += x[j]; sq += x[j] * x[j]; }
#pragma unroll
  for (int off = 1; off < 64; off <<= 1) {
    s += __shfl_xor(s, off, 64);
    sq += __shfl_xor(sq, off, 64);
  }
  const float mean = s * (1.f / 512.f);
  const float var = sq * (1.f / 512.f) - mean * mean;
  const float rstd = rsqrtf(var + 1e-6f);
  float4 g0 = *(const float4*)(gam + d0), g1v = *(const float4*)(gam + d0 + 4);
  float4 b0 = *(const float4*)(bet + d0), b1v = *(const float4*)(bet + d0 + 4);
  float gg[8] = {g0.x, g0.y, g0.z, g0.w, g1v.x, g1v.y, g1v.z, g1v.w};
  float bb2[8] = {b0.x, b0.y, b0.z, b0.w, b1v.x, b1v.y, b1v.z, b1v.w};
  bf16x8_t ov;
#pragma unroll
  for (int j = 0; j < 8; j++)
    ov[j] = (__bf16)((x[j] - mean) * rstd * gg[j] + bb2[j]);
  *(bf16x8_t*)(Ob + (size_t)t * DD + d0) = ov;
}

// ---------------- fused LN2 + final projection:
// r = LN(X) -> o_r (fp32) AND pred = r @ Wfin + bfin -> P1,P2 (no o_r re-read)
__global__ __launch_bounds__(256) void ln_final_kernel(
    const __bf16* __restrict__ X, const float* __restrict__ gam,
    const float* __restrict__ bet, float* __restrict__ Of,
    const float* __restrict__ Wfin, const float* __restrict__ bfin,
    float* __restrict__ P1, float* __restrict__ P2) {
  __shared__ float wfs[512][16];
  __shared__ float rf[4][516];           // +4 pad: de-bank the k-column reads
  for (int i = threadIdx.x; i < 512 * 16; i += 256) wfs[i >> 4][i & 15] = Wfin[i];
  const int tw = threadIdx.x >> 6;       // token slot within block
  const int t = blockIdx.x * 4 + tw;
  const int lane = threadIdx.x & 63;
  const int d0 = lane * 8;
  bf16x8_t xv = *(const bf16x8_t*)(X + (size_t)t * DD + d0);
  float x[8];
#pragma unroll
  for (int j = 0; j < 8; j++) x[j] = (float)xv[j];
  float s = 0.f, sq = 0.f;
#pragma unroll
  for (int j = 0; j < 8; j++) { s += x[j]; sq += x[j] * x[j]; }
#pragma unroll
  for (int off = 1; off < 64; off <<= 1) {
    s += __shfl_xor(s, off, 64);
    sq += __shfl_xor(sq, off, 64);
  }
  const float mean = s * (1.f / 512.f);
  const float var = sq * (1.f / 512.f) - mean * mean;
  const float rstd = rsqrtf(var + 1e-6f);
  float4 g0 = *(const float4*)(gam + d0), g1v = *(const float4*)(gam + d0 + 4);
  float4 b0 = *(const float4*)(bet + d0), b1v = *(const float4*)(bet + d0 + 4);
  float gg[8] = {g0.x, g0.y, g0.z, g0.w, g1v.x, g1v.y, g1v.z, g1v.w};
  float bb2[8] = {b0.x, b0.y, b0.z, b0.w, b1v.x, b1v.y, b1v.z, b1v.w};
  float o[8];
  float4 f0, f1;
#pragma unroll
  for (int j = 0; j < 8; j++) {
    o[j] = (x[j] - mean) * rstd * gg[j] + bb2[j];
    rf[tw][d0 + j] = o[j];
  }
  f0.x = o[0]; f0.y = o[1]; f0.z = o[2]; f0.w = o[3];
  f1.x = o[4]; f1.y = o[5]; f1.z = o[6]; f1.w = o[7];
  *(float4*)(Of + (size_t)t * DD + d0) = f0;
  *(float4*)(Of + (size_t)t * DD + d0 + 4) = f1;
  __syncthreads();
  if (threadIdx.x < 64) {
    const int tt = threadIdx.x >> 4, n = threadIdx.x & 15;
    float acc = 0.f;
#pragma unroll 4
    for (int k = 0; k < 512; k += 4) {
      const float4 rv = *(const float4*)&rf[tt][k];
      acc += rv.x * wfs[k][n] + rv.y * wfs[k + 1][n] +
             rv.z * wfs[k + 2][n] + rv.w * wfs[k + 3][n];
    }
    const float v = acc + bfin[n];
    const size_t tok = (size_t)blockIdx.x * 4 + tt;
    P1[tok * 16 + n] = v;
    P2[tok * 16 + n] = v;
  }
}

extern "C" void kernel_launch(void* const* d_in, const int* in_sizes, int n_in,
                              void* d_out, int out_size, void* d_ws, size_t ws_size,
                              hipStream_t stream) {
  const float* inp  = (const float*)d_in[0];
  const float* Wp   = (const float*)d_in[2];
  const float* bp   = (const float*)d_in[3];
  const float* Wq   = (const float*)d_in[4];
  const float* bq   = (const float*)d_in[5];
  const float* Wk   = (const float*)d_in[6];
  const float* bk   = (const float*)d_in[7];
  const float* Wv   = (const float*)d_in[8];
  const float* bv   = (const float*)d_in[9];
  const float* Wo   = (const float*)d_in[10];
  const float* bo   = (const float*)d_in[11];
  const float* g1   = (const float*)d_in[12];
  const float* be1  = (const float*)d_in[13];
  const float* g2   = (const float*)d_in[14];
  const float* be2  = (const float*)d_in[15];
  const float* Wf1  = (const float*)d_in[16];
  const float* bf1  = (const float*)d_in[17];
  const float* Wf2  = (const float*)d_in[18];
  const float* bf2  = (const float*)d_in[19];
  const float* Wfin = (const float*)d_in[20];
  const float* bfin = (const float*)d_in[21];
  (void)in_sizes; (void)n_in; (void)out_size; (void)ws_size;

  float* out = (float*)d_out;
  float* o_pred1 = out;                    // (B,P,S,16)
  float* o_pred2 = out + 262144;
  float* o_k     = out + 524288;           // (B,P,S,512)
  float* o_v     = out + 8912896;
  float* o_r     = out + 17301504;
  float* o_att   = out + 25690112;         // (B,P,S,S)

  // workspace carve-up (~170 MB)
  char* base = (char*)d_ws;
  size_t off = 0;
  auto takeB = [&](size_t bytes) -> char* {
    char* p = base + off;
    off += (bytes + 255) & ~(size_t)255;
    return p;
  };
  float*  Wfold = (float*)takeB((size_t)16 * 1536 * 4);
  float*  bfold = (float*)takeB((size_t)1536 * 4);
  __bf16* Wo_t  = (__bf16*)takeB((size_t)DD * DD * 2);
  __bf16* Wf1_t = (__bf16*)takeB((size_t)DD * DFFX * 2);
  __bf16* Wf2_t = (__bf16*)takeB((size_t)DD * DFFX * 2);
  __bf16* xb    = (__bf16*)takeB((size_t)TT * DD * 2);
  __bf16* qbuf  = (__bf16*)takeB((size_t)TT * DD * 2);
  __bf16* kbuf  = (__bf16*)takeB((size_t)TT * DD * 2);
  __bf16* vbuf  = (__bf16*)takeB((size_t)TT * DD * 2);
  __bf16* vwt   = (__bf16*)takeB((size_t)TT * DD * 2);   // V@Wo transposed [z][D][S]
  __bf16* h1b   = (__bf16*)takeB((size_t)TT * DD * 2);
  __bf16* lninb = (__bf16*)takeB((size_t)TT * DD * 2);
  __bf16* ffb   = (__bf16*)takeB((size_t)TT * DFFX * 2);
  __bf16* pb    = ffb;  // bf16 scores->probs alias FFN scratch (same element
                        // count; pb dead before FFN1 writes ffb)

  // weights -> bf16 transposed [N][K], one merged launch
  transpose_conv3<<<dim3(2304), 256, 0, stream>>>(Wo, Wf1, Wf2, Wo_t, Wf1_t, Wf2_t);

  // fold Wp into Wq/Wk/Wv:  q|k|v = inp @ Wfold + bfold  (K=16)
  fold_kernel<<<dim3(96), 256, 0, stream>>>(Wp, bp, Wq, bq, Wk, bk, Wv, bv,
                                            Wfold, bfold);

  // q,k,v (+ fp32 o_k/o_v) and x residual, one K=16 launch (4 slices)
  smallk_kernel<<<dim3(TT / 16, 4), 256, 0, stream>>>(
      inp, Wfold, bfold, Wp, bp, qbuf, kbuf, vbuf, xb, o_k, o_v);

  // combined: scores -> bf16 pb (tri) AND VWo^T -> vwt, one launch
  attn_prep_kernel<<<dim3(20, 16, BB), 256, 0, stream>>>(
      qbuf, kbuf, vbuf, Wo_t, pb, vwt);

  // softmax: bf16 scores (pb) -> fp32 probs (o_att, zeros above diag) + bf16 pb
  softmax_kernel<<<dim3(TT / 4), 256, 0, stream>>>(o_att, pb);

  // PV' = P @ VWo + bo + x -> LN1 input. 512 blocks (2/CU), greedy balance +
  // XCD-chunked remap (4*16=64 %8==0); causal nt = 4..16 per block.
  gemm128<true, false, true, true><<<dim3(4, 16, BB), 256, 0, stream>>>(
      pb, vwt, bo, xb, lninb, DD, SS,
      (size_t)SS * SS, (size_t)DD * SS, (size_t)SS * DD);

  // LN1
  ln_kernel<<<dim3(TT / 4), 256, 0, stream>>>(lninb, g1, be1, h1b);

  // FFN with XCD-chunked block swizzle (A-panel L2 reuse within XCD)
  gemm128<false, true, false, true><<<dim3(16, 128, 1), 256, 0, stream>>>(
      h1b, Wf1_t, bf1, nullptr, ffb, DFFX, DD, 0, 0, 0);
  gemm128<false, false, true, true><<<dim3(4, 128, 1), 256, 0, stream>>>(
      ffb, Wf2_t, bf2, h1b, lninb, DD, DFFX, 0, 0, 0);

  // fused LN2 -> r (fp32 output) + final projection -> pred (both slots)
  ln_final_kernel<<<dim3(TT / 4), 256, 0, stream>>>(
      lninb, g2, be2, o_r, Wfin, bfin, o_pred1, o_pred2);
}

// Round 13
// 423.472 us; speedup vs baseline: 1.3418x; 1.0289x over previous
//
#include <hip/hip_runtime.h>
#include <hip/hip_bf16.h>
#include <stdint.h>

// Problem dims (SMC transformer, noise=False => causal self-attention)
#define BB 8
#define SS 2048
#define TT (BB*SS)       // 16384 tokens total (P=1)
#define DD 512
#define DFFX 2048

static __device__ const float SQRTD  = 22.627416997969522f;   // sqrt(512)
static __device__ const float INVSQD = 0.04419417382415922f;  // 1/sqrt(512)

typedef __attribute__((ext_vector_type(4))) float  f32x4_t;
typedef __attribute__((ext_vector_type(8))) __bf16 bf16x8_t;
typedef __attribute__((ext_vector_type(4))) __bf16 bf16x4_t;
typedef __attribute__((ext_vector_type(2))) __bf16 bf16x2_t;

// MFMA 16x16x32 bf16 operand layout (gfx950), HW-verified rounds 1-12:
//   A: lane l, elem e -> A[l&15][4*(l>>4) + (e&3) + 16*(e>>2)]
//   B: lane l, elem e -> B[4*(l>>4) + (e&3) + 16*(e>>2)][l&15]
//   D: lane l, reg  r -> D[4*(l>>4) + r][l&15]
static __device__ __forceinline__ bf16x8_t mk_frag(bf16x4_t lo, bf16x4_t hi) {
  return __builtin_shufflevector(lo, hi, 0, 1, 2, 3, 4, 5, 6, 7);
}

// async global->LDS, 16B per lane, dest = uniform base + lane*16
typedef __attribute__((address_space(1))) const unsigned int g_u32;
typedef __attribute__((address_space(3))) unsigned int lds_u32;
static __device__ __forceinline__ void gld16(const void* g, void* l) {
  __builtin_amdgcn_global_load_lds((g_u32*)g, (lds_u32*)l, 16, 0, 0);
}

// ---------------- merged weight transpose+convert for Wo/Wf1/Wf2:
// dst[C][R] (bf16) = src[R][C] (f32); 2304 blocks, segment decoded from bx.
__global__ __launch_bounds__(256) void transpose_conv3(
    const float* __restrict__ Wo, const float* __restrict__ Wf1,
    const float* __restrict__ Wf2, __bf16* __restrict__ Wo_t,
    __bf16* __restrict__ Wf1_t, __bf16* __restrict__ Wf2_t) {
  const int bx = blockIdx.x;
  const float* src; __bf16* dst; int C, R, gx, gy;
  if (bx < 256)       { src = Wo;  dst = Wo_t;  R = 512;  C = 512;  gx = bx & 15;  gy = bx >> 4; }
  else if (bx < 1280) { const int b = bx - 256;  src = Wf1; dst = Wf1_t; R = 512;  C = 2048; gx = b & 63; gy = b >> 6; }
  else                { const int b = bx - 1280; src = Wf2; dst = Wf2_t; R = 2048; C = 512;  gx = b & 15; gy = b >> 4; }
  __shared__ float tile[32][33];
  const int c0 = gx * 32, r0 = gy * 32;
  const int tx = threadIdx.x & 31, ty = threadIdx.x >> 5;
#pragma unroll
  for (int i = 0; i < 4; i++)
    tile[ty + 8*i][tx] = src[(size_t)(r0 + ty + 8*i) * C + c0 + tx];
  __syncthreads();
#pragma unroll
  for (int i = 0; i < 4; i++)
    dst[(size_t)(c0 + ty + 8*i) * R + r0 + tx] = (__bf16)tile[tx][ty + 8*i];
}

// ---------------- fold: Wfold[r][c] = sqrt(d) * (Wp @ W{q,k,v})[r][c]  (16x1536)
//                  bfold[c] = sqrt(d) * (bp @ W)[c] + b[c]
__global__ __launch_bounds__(256) void fold_kernel(
    const float* __restrict__ Wp, const float* __restrict__ bp,
    const float* __restrict__ Wq, const float* __restrict__ bq,
    const float* __restrict__ Wk, const float* __restrict__ bk,
    const float* __restrict__ Wv, const float* __restrict__ bv,
    float* __restrict__ Wfold, float* __restrict__ bfold) {
  __shared__ float wp[16][512];
  __shared__ float bps[512];
  for (int i = threadIdx.x; i < 16 * 512; i += 256) wp[i >> 9][i & 511] = Wp[i];
  for (int i = threadIdx.x; i < 512; i += 256) bps[i] = bp[i];
  __syncthreads();
  const int cl = threadIdx.x & 15, r = threadIdx.x >> 4;
  const int cg = blockIdx.x * 16 + cl;           // 0..1535
  const int sub = cg >> 9, wc = cg & 511;        // uniform per block
  const float* W = sub == 0 ? Wq : sub == 1 ? Wk : Wv;
  const float* bb = sub == 0 ? bq : sub == 1 ? bk : bv;
  float acc = 0.f, bacc = 0.f;
  for (int k = 0; k < 512; k += 4) {
    const float4 wpv = *(const float4*)&wp[r][k];
    const float g0 = W[(size_t)k * 512 + wc];
    const float g1 = W[(size_t)(k + 1) * 512 + wc];
    const float g2 = W[(size_t)(k + 2) * 512 + wc];
    const float g3 = W[(size_t)(k + 3) * 512 + wc];
    acc += wpv.x * g0 + wpv.y * g1 + wpv.z * g2 + wpv.w * g3;
    if (r == 0) {
      const float4 b4 = *(const float4*)&bps[k];
      bacc += b4.x * g0 + b4.y * g1 + b4.z * g2 + b4.w * g3;
    }
  }
  Wfold[(size_t)r * 1536 + cg] = acc * SQRTD;
  if (r == 0) bfold[cg] = bacc * SQRTD + bb[wc];
}

// ---------------- small-K (K=16) dense, 4 slices: sl 0/1/2 = q/k/v via Wfold
// (ldw=1536), sl 3 = x via Wp (ldw=512, scale=sqrt(d)). 16 tokens/block;
// thread owns 2 cols with the 16x2 weight block in VGPRs.
__global__ __launch_bounds__(256) void smallk_kernel(
    const float* __restrict__ inp,
    const float* __restrict__ Wfold, const float* __restrict__ bfold,
    const float* __restrict__ Wp, const float* __restrict__ bp,
    __bf16* __restrict__ qb, __bf16* __restrict__ kb, __bf16* __restrict__ vb,
    __bf16* __restrict__ xb, float* __restrict__ o_k, float* __restrict__ o_v) {
  const int sl = blockIdx.y;
  const float* W; const float* bias; int ldw; float scale;
  __bf16* ob; float* fo;
  if (sl == 3) { W = Wp; bias = bp; ldw = 512; scale = SQRTD; ob = xb; fo = nullptr; }
  else {
    W = Wfold + sl * 512; bias = bfold + sl * 512; ldw = 1536; scale = 1.f;
    ob = sl == 0 ? qb : sl == 1 ? kb : vb;
    fo = sl == 0 ? (float*)nullptr : sl == 1 ? o_k : o_v;
  }
  __shared__ float ivl[16][16];
  const int tid = threadIdx.x;
  ivl[tid >> 4][tid & 15] = inp[(size_t)blockIdx.x * 256 + tid];
  const int c0 = 2 * tid;
  float w0[16], w1[16];
#pragma unroll
  for (int r = 0; r < 16; r++) {
    w0[r] = W[(size_t)r * ldw + c0];
    w1[r] = W[(size_t)r * ldw + c0 + 1];
  }
  const float bb0 = bias[c0], bb1 = bias[c0 + 1];
  __syncthreads();
#pragma unroll 4
  for (int tt = 0; tt < 16; ++tt) {
    const float4 i0 = *(const float4*)&ivl[tt][0];
    const float4 i1 = *(const float4*)&ivl[tt][4];
    const float4 i2 = *(const float4*)&ivl[tt][8];
    const float4 i3 = *(const float4*)&ivl[tt][12];
    float a0, a1;
    a0  = i0.x * w0[0];   a1  = i0.x * w1[0];
    a0 += i0.y * w0[1];   a1 += i0.y * w1[1];
    a0 += i0.z * w0[2];   a1 += i0.z * w1[2];
    a0 += i0.w * w0[3];   a1 += i0.w * w1[3];
    a0 += i1.x * w0[4];   a1 += i1.x * w1[4];
    a0 += i1.y * w0[5];   a1 += i1.y * w1[5];
    a0 += i1.z * w0[6];   a1 += i1.z * w1[6];
    a0 += i1.w * w0[7];   a1 += i1.w * w1[7];
    a0 += i2.x * w0[8];   a1 += i2.x * w1[8];
    a0 += i2.y * w0[9];   a1 += i2.y * w1[9];
    a0 += i2.z * w0[10];  a1 += i2.z * w1[10];
    a0 += i2.w * w0[11];  a1 += i2.w * w1[11];
    a0 += i3.x * w0[12];  a1 += i3.x * w1[12];
    a0 += i3.y * w0[13];  a1 += i3.y * w1[13];
    a0 += i3.z * w0[14];  a1 += i3.z * w1[14];
    a0 += i3.w * w0[15];  a1 += i3.w * w1[15];
    const float v0 = (a0 + bb0) * scale;
    const float v1 = (a1 + bb1) * scale;
    const size_t t = (size_t)blockIdx.x * 16 + tt;
    bf16x2_t pv; pv[0] = (__bf16)v0; pv[1] = (__bf16)v1;
    *(bf16x2_t*)(ob + t * 512 + c0) = pv;
    if (fo) {
      float2 fv; fv.x = v0; fv.y = v1;
      *(float2*)(fo + t * 512 + c0) = fv;
    }
  }
}

// ---------------- combined attention-prep: ONE launch covering
//   role A (bx<16):  scores = q @ k^T / sqrt(d) -> bf16 pb (tri-skip)
//   role B (bx>=16): VWo^T = (v @ Wo)^T -> vwt (transposed store)
// Both are K=512 GEMMs sharing the verified 3-buffer ring; VWo blocks backfill
// the CUs left idle by score's upper-triangle skip. NO XCD remap: default
// round-robin dispatch interleaves heavy/light m-bands across XCDs (the R11/12
// chunked remap concentrated live blocks on high-m XCDs -> ~3.5x load skew).
__global__ __launch_bounds__(256) void attn_prep_kernel(
    const __bf16* __restrict__ qbuf, const __bf16* __restrict__ kbuf,
    const __bf16* __restrict__ vbuf, const __bf16* __restrict__ Wo_t,
    __bf16* __restrict__ pb, __bf16* __restrict__ vwt) {
  const int bx = blockIdx.x, by = blockIdx.y;
  const int z = blockIdx.z;
  const int m0 = by * 128;
  const bool isScore = bx < 16;
  const int n0 = (isScore ? bx : bx - 16) * 128;
  if (isScore && n0 > m0 + 127) return;
  const __bf16* A  = (isScore ? qbuf : vbuf) + (size_t)z * SS * DD;
  const __bf16* Bt = isScore ? (kbuf + (size_t)z * SS * DD) : Wo_t;
  constexpr int K = DD;   // 512 for both roles

  __shared__ __align__(16) __bf16 As[3 * 128 * 32];
  __shared__ __align__(16) __bf16 Bs[3 * 128 * 32];
  const int tid = threadIdx.x, lane = tid & 63, wave = tid >> 6;
  const int l15 = lane & 15, g = lane >> 4;
  const int wr = wave >> 1, wc = wave & 1;

  const int srow0 = wave * 32 + (lane >> 2);
  const int srow1 = srow0 + 16;
  const int sc0 = (((lane & 3) ^ ((srow0 >> 1) & 3)) << 4);
  const int sc1 = (((lane & 3) ^ ((srow1 >> 1) & 3)) << 4);
  const char* ga0 = (const char*)(A + (size_t)(m0 + srow0) * K) + sc0;
  const char* ga1 = (const char*)(A + (size_t)(m0 + srow1) * K) + sc1;
  const char* gb0 = (const char*)(Bt + (size_t)(n0 + srow0) * K) + sc0;
  const char* gb1 = (const char*)(Bt + (size_t)(n0 + srow1) * K) + sc1;

  const int plo = (g >> 1) ^ ((l15 >> 1) & 3);
  const int aof0 = (wr * 64 + l15) * 64 + plo * 16 + (g & 1) * 8;
  const int bof0 = (wc * 64 + l15) * 64 + plo * 16 + (g & 1) * 8;

  f32x4_t acc[4][4];
#pragma unroll
  for (int i = 0; i < 4; i++)
#pragma unroll
    for (int j = 0; j < 4; j++) acc[i][j] = (f32x4_t){0.f, 0.f, 0.f, 0.f};

  auto STAGE = [&](const int buf, const int k0) {
    const size_t kb = (size_t)k0 * 2;
    char* la = (char*)As + buf * 8192 + wave * 2048;
    char* lb = (char*)Bs + buf * 8192 + wave * 2048;
    gld16(ga0 + kb, la);
    gld16(ga1 + kb, la + 1024);
    gld16(gb0 + kb, lb);
    gld16(gb1 + kb, lb + 1024);
  };
  auto COMPUTE = [&](const int buf) {
    const char* AsB = (const char*)As + buf * 8192;
    const char* BsB = (const char*)Bs + buf * 8192;
    bf16x8_t af[4], bfr[4];
#pragma unroll
    for (int i = 0; i < 4; i++) {
      const int ao = aof0 + i * 1024;
      af[i] = mk_frag(*(const bf16x4_t*)(AsB + ao),
                      *(const bf16x4_t*)(AsB + (ao ^ 32)));
      const int bo = bof0 + i * 1024;
      bfr[i] = mk_frag(*(const bf16x4_t*)(BsB + bo),
                       *(const bf16x4_t*)(BsB + (bo ^ 32)));
    }
#pragma unroll
    for (int i = 0; i < 4; i++)
#pragma unroll
      for (int j = 0; j < 4; j++)
        acc[i][j] = __builtin_amdgcn_mfma_f32_16x16x32_bf16(af[i], bfr[j], acc[i][j], 0, 0, 0);
  };

  const int nt = K >> 5;    // 16
  STAGE(0, 0);
  STAGE(1, 32);
  STAGE(2, 64);
  int cur = 0;
  for (int t = 0; t < nt; ++t) {
    const int rem = nt - 1 - t;
    if (rem >= 2)      asm volatile("s_waitcnt vmcnt(8)" ::: "memory");
    else if (rem == 1) asm volatile("s_waitcnt vmcnt(4)" ::: "memory");
    else               asm volatile("s_waitcnt vmcnt(0)" ::: "memory");
    __builtin_amdgcn_s_barrier();
    COMPUTE(cur);
    __builtin_amdgcn_s_barrier();
    if (t + 3 < nt) STAGE(cur, (t + 3) << 5);
    cur = (cur == 2) ? 0 : cur + 1;
  }

#pragma unroll
  for (int i = 0; i < 4; i++) {
#pragma unroll
    for (int j = 0; j < 4; j++) {
      const int col = n0 + wc * 64 + j * 16 + l15;
      if (isScore) {
#pragma unroll
        for (int r = 0; r < 4; r++) {
          const int row = m0 + wr * 64 + i * 16 + g * 4 + r;
          pb[(size_t)z * SS * SS + (size_t)row * SS + col] =
              (__bf16)(acc[i][j][r] * INVSQD);
        }
      } else {
        const int row0 = m0 + wr * 64 + i * 16 + g * 4;
        bf16x4_t tv;
#pragma unroll
        for (int r = 0; r < 4; r++) tv[r] = (__bf16)acc[i][j][r];
        *(bf16x4_t*)(vwt + (size_t)z * SS * DD + (size_t)col * SS + row0) = tv;
      }
    }
  }
}

// ---------------- 128x128-tile MFMA GEMM, 3-buffer ring + counted vmcnt (T4).
// CAUSAL: k-loop ends at m0+128 (PV); launch with XCDS=false — default
// round-robin dispatch balances the triangular load across XCDs.
// RELU: relu(acc+bias).  RES: += Res.
// XCDS: bijective XCD-chunked remap — ONLY for uniform-work grids (FFN).
template <bool CAUSAL, bool RELU, bool RES, bool XCDS>
__global__ __launch_bounds__(256) void gemm128(
    const __bf16* __restrict__ A, const __bf16* __restrict__ Bt,
    const float* __restrict__ bias, const __bf16* __restrict__ Res,
    __bf16* __restrict__ Cb,
    int N, int K, size_t aBatch, size_t bBatch, size_t cBatch) {
  int bx = blockIdx.x, by = blockIdx.y;
  if (XCDS) {
    const int nwg = (int)(gridDim.x * gridDim.y);
    const int cpx = nwg >> 3;
    const int lin = (int)(blockIdx.y * gridDim.x + blockIdx.x);
    const int nl = (lin & 7) * cpx + (lin >> 3);
    by = nl / (int)gridDim.x;
    bx = nl - by * (int)gridDim.x;
  }
  const int n0 = bx * 128;
  const int m0 = by * 128;
  __shared__ __align__(16) __bf16 As[3 * 128 * 32];   // 3 x 8 KB
  __shared__ __align__(16) __bf16 Bs[3 * 128 * 32];
  const int tid = threadIdx.x, lane = tid & 63, wave = tid >> 6;
  const int l15 = lane & 15, g = lane >> 4;
  const int wr = wave >> 1, wc = wave & 1;

  const int srow0 = wave * 32 + (lane >> 2);
  const int srow1 = srow0 + 16;
  const int sc0 = (((lane & 3) ^ ((srow0 >> 1) & 3)) << 4);
  const int sc1 = (((lane & 3) ^ ((srow1 >> 1) & 3)) << 4);
  const size_t aOff = (size_t)blockIdx.z * aBatch;
  const size_t bOff = (size_t)blockIdx.z * bBatch;
  const size_t cOff = (size_t)blockIdx.z * cBatch;
  const char* gb0 = (const char*)(Bt + bOff + (size_t)(n0 + srow0) * K) + sc0;
  const char* gb1 = (const char*)(Bt + bOff + (size_t)(n0 + srow1) * K) + sc1;
  const char* ga0 = (const char*)(A + aOff + (size_t)(m0 + srow0) * K) + sc0;
  const char* ga1 = (const char*)(A + aOff + (size_t)(m0 + srow1) * K) + sc1;

  const int plo = (g >> 1) ^ ((l15 >> 1) & 3);
  const int aof0 = (wr * 64 + l15) * 64 + plo * 16 + (g & 1) * 8;
  const int bof0 = (wc * 64 + l15) * 64 + plo * 16 + (g & 1) * 8;

  f32x4_t acc[4][4];
#pragma unroll
  for (int i = 0; i < 4; i++)
#pragma unroll
    for (int j = 0; j < 4; j++) acc[i][j] = (f32x4_t){0.f, 0.f, 0.f, 0.f};

  auto STAGE = [&](const int buf, const int k0) {
    const size_t kb = (size_t)k0 * 2;
    char* la = (char*)As + buf * 8192 + wave * 2048;
    char* lb = (char*)Bs + buf * 8192 + wave * 2048;
    gld16(ga0 + kb, la);
    gld16(ga1 + kb, la + 1024);
    gld16(gb0 + kb, lb);
    gld16(gb1 + kb, lb + 1024);
  };
  auto COMPUTE = [&](const int buf) {
    const char* AsB = (const char*)As + buf * 8192;
    const char* BsB = (const char*)Bs + buf * 8192;
    bf16x8_t af[4], bfr[4];
#pragma unroll
    for (int i = 0; i < 4; i++) {
      const int ao = aof0 + i * 1024;
      af[i] = mk_frag(*(const bf16x4_t*)(AsB + ao),
                      *(const bf16x4_t*)(AsB + (ao ^ 32)));
      const int bo = bof0 + i * 1024;
      bfr[i] = mk_frag(*(const bf16x4_t*)(BsB + bo),
                       *(const bf16x4_t*)(BsB + (bo ^ 32)));
    }
#pragma unroll
    for (int i = 0; i < 4; i++)
#pragma unroll
      for (int j = 0; j < 4; j++)
        acc[i][j] = __builtin_amdgcn_mfma_f32_16x16x32_bf16(af[i], bfr[j], acc[i][j], 0, 0, 0);
  };

  const int kend = CAUSAL ? (m0 + 128) : K;
  const int nt = kend >> 5;           // >= 4 at every call site
  STAGE(0, 0);
  STAGE(1, 32);
  STAGE(2, 64);
  int cur = 0;
  for (int t = 0; t < nt; ++t) {
    const int rem = nt - 1 - t;
    if (rem >= 2)      asm volatile("s_waitcnt vmcnt(8)" ::: "memory");
    else if (rem == 1) asm volatile("s_waitcnt vmcnt(4)" ::: "memory");
    else               asm volatile("s_waitcnt vmcnt(0)" ::: "memory");
    __builtin_amdgcn_s_barrier();     // tile t visible everywhere
    COMPUTE(cur);
    __builtin_amdgcn_s_barrier();     // all reads of buf `cur` done
    if (t + 3 < nt) STAGE(cur, (t + 3) << 5);
    cur = (cur == 2) ? 0 : cur + 1;
  }

#pragma unroll
  for (int i = 0; i < 4; i++) {
#pragma unroll
    for (int j = 0; j < 4; j++) {
      const int col = n0 + wc * 64 + j * 16 + l15;
      const float bv = bias ? bias[col] : 0.f;
#pragma unroll
      for (int r = 0; r < 4; r++) {
        const int row = m0 + wr * 64 + i * 16 + g * 4 + r;
        float v = acc[i][j][r] + bv;
        if (RELU) v = fmaxf(v, 0.f);
        if (RES) v += (float)Res[cOff + (size_t)row * N + col];
        Cb[cOff + (size_t)row * N + col] = (__bf16)v;
      }
    }
  }
}

// ---------------- row softmax: reads bf16 scores from pb (lower-tri valid),
// writes fp32 probs to att (full row, exact zeros above diag) + bf16 probs
// back into pb in place (only chunks PV will read). One wave per row.
__global__ __launch_bounds__(256) void softmax_kernel(
    float* __restrict__ att, __bf16* __restrict__ pb) {
  const int t = blockIdx.x * 4 + (threadIdx.x >> 6);   // global row (b*2048+q)
  const int gq = t & (SS - 1);                         // query index in batch
  const int lane = threadIdx.x & 63;
  float* row = att + (size_t)t * SS;
  __bf16* prow = pb + (size_t)t * SS;
  const int nch = (gq >> 9) + 1;   // 512-wide chunks containing valid cols
  const int wlim = ((gq & ~127) + 128 + 511) >> 9;
  float x[32];
  float m = -1e30f;
#pragma unroll
  for (int ch = 0; ch < 4; ch++) {
    float* xp = &x[ch * 8];
    if (ch < nch) {
      const int c0 = ch * 512 + lane * 8;
      bf16x8_t v = *(const bf16x8_t*)(prow + c0);
#pragma unroll
      for (int j = 0; j < 8; j++) {
        const float f = (float)v[j];
        xp[j] = (c0 + j <= gq) ? f : -1e30f;  // select: immune to garbage
        m = fmaxf(m, xp[j]);
      }
    } else {
#pragma unroll
      for (int j = 0; j < 8; j++) xp[j] = -1e30f;
    }
  }
#pragma unroll
  for (int off = 1; off < 64; off <<= 1) m = fmaxf(m, __shfl_xor(m, off, 64));
  float s = 0.f;
#pragma unroll
  for (int i = 0; i < 32; i++) { x[i] = __expf(x[i] - m); s += x[i]; }
#pragma unroll
  for (int off = 1; off < 64; off <<= 1) s += __shfl_xor(s, off, 64);
  const float inv = 1.f / s;
#pragma unroll
  for (int ch = 0; ch < 4; ch++) {
    const int c0 = ch * 512 + lane * 8;
    float o[8];
    bf16x8_t ov;
#pragma unroll
    for (int j = 0; j < 8; j++) {
      const float pv = x[ch * 8 + j] * inv;  // masked entries exactly 0
      o[j] = pv;
      ov[j] = (__bf16)pv;
    }
    float4 f0, f1;
    f0.x = o[0]; f0.y = o[1]; f0.z = o[2]; f0.w = o[3];
    f1.x = o[4]; f1.y = o[5]; f1.z = o[6]; f1.w = o[7];
    *(float4*)(row + c0) = f0;
    *(float4*)(row + c0 + 4) = f1;
    if (ch < wlim) *(bf16x8_t*)(prow + c0) = ov;
  }
}

// ---------------- LayerNorm over D=512 (population var, eps inside sqrt)
__global__ __launch_bounds__(256) void ln_kernel(
    const __bf16* __restrict__ X, const float* __restrict__ gam,
    const float* __restrict__ bet, __bf16* __restrict__ Ob) {
  const int t = blockIdx.x * 4 + (threadIdx.x >> 6);
  const int lane = threadIdx.x & 63;
  const int d0 = lane * 8;
  bf16x8_t xv = *(const bf16x8_t*)(X + (size_t)t * DD + d0);
  float x[8];
#pragma unroll
  for (int j = 0; j < 8; j++) x[j] = (float)xv[j];
  float s = 0.f, sq = 0.f;
#pragma unroll
  for (int j = 0; j < 8; j++) { s += x[j]; sq += x[j] * x[j]; }
#pragma unroll
  for (int off = 1; off < 64; off <<= 1) {
    s += __shfl_xor(s, off, 64);
    sq += __shfl_xor(sq, off, 64);
  }
  const float mean = s * (1.f / 512.f);
  const float var = sq * (1.f / 512.f) - mean * mean;
  const float rstd = rsqrtf(var + 1e-6f);
  float4 g0 = *(const float4*)(gam + d0), g1v = *(const float4*)(gam + d0 + 4);
  float4 b0 = *(const float4*)(bet + d0), b1v = *(const float4*)(bet + d0 + 4);
  float gg[8] = {g0.x, g0.y, g0.z, g0.w, g1v.x, g1v.y, g1v.z, g1v.w};
  float bb2[8] = {b0.x, b0.y, b0.z, b0.w, b1v.x, b1v.y, b1v.z, b1v.w};
  bf16x8_t ov;
#pragma unroll
  for (int j = 0; j < 8; j++)
    ov[j] = (__bf16)((x[j] - mean) * rstd * gg[j] + bb2[j]);
  *(bf16x8_t*)(Ob + (size_t)t * DD + d0) = ov;
}

// ---------------- fused LN2 + final projection:
// r = LN(X) -> o_r (fp32) AND pred = r @ Wfin + bfin -> P1,P2 (no o_r re-read)
__global__ __launch_bounds__(256) void ln_final_kernel(
    const __bf16* __restrict__ X, const float* __restrict__ gam,
    const float* __restrict__ bet, float* __restrict__ Of,
    const float* __restrict__ Wfin, const float* __restrict__ bfin,
    float* __restrict__ P1, float* __restrict__ P2) {
  __shared__ float wfs[512][16];
  __shared__ float rf[4][516];           // +4 pad: de-bank the k-column reads
  for (int i = threadIdx.x; i < 512 * 16; i += 256) wfs[i >> 4][i & 15] = Wfin[i];
  const int tw = threadIdx.x >> 6;       // token slot within block
  const int t = blockIdx.x * 4 + tw;
  const int lane = threadIdx.x & 63;
  const int d0 = lane * 8;
  bf16x8_t xv = *(const bf16x8_t*)(X + (size_t)t * DD + d0);
  float x[8];
#pragma unroll
  for (int j = 0; j < 8; j++) x[j] = (float)xv[j];
  float s = 0.f, sq = 0.f;
#pragma unroll
  for (int j = 0; j < 8; j++) { s += x[j]; sq += x[j] * x[j]; }
#pragma unroll
  for (int off = 1; off < 64; off <<= 1) {
    s += __shfl_xor(s, off, 64);
    sq += __shfl_xor(sq, off, 64);
  }
  const float mean = s * (1.f / 512.f);
  const float var = sq * (1.f / 512.f) - mean * mean;
  const float rstd = rsqrtf(var + 1e-6f);
  float4 g0 = *(const float4*)(gam + d0), g1v = *(const float4*)(gam + d0 + 4);
  float4 b0 = *(const float4*)(bet + d0), b1v = *(const float4*)(bet + d0 + 4);
  float gg[8] = {g0.x, g0.y, g0.z, g0.w, g1v.x, g1v.y, g1v.z, g1v.w};
  float bb2[8] = {b0.x, b0.y, b0.z, b0.w, b1v.x, b1v.y, b1v.z, b1v.w};
  float o[8];
  float4 f0, f1;
#pragma unroll
  for (int j = 0; j < 8; j++) {
    o[j] = (x[j] - mean) * rstd * gg[j] + bb2[j];
    rf[tw][d0 + j] = o[j];
  }
  f0.x = o[0]; f0.y = o[1]; f0.z = o[2]; f0.w = o[3];
  f1.x = o[4]; f1.y = o[5]; f1.z = o[6]; f1.w = o[7];
  *(float4*)(Of + (size_t)t * DD + d0) = f0;
  *(float4*)(Of + (size_t)t * DD + d0 + 4) = f1;
  __syncthreads();
  if (threadIdx.x < 64) {
    const int tt = threadIdx.x >> 4, n = threadIdx.x & 15;
    float acc = 0.f;
#pragma unroll 4
    for (int k = 0; k < 512; k += 4) {
      const float4 rv = *(const float4*)&rf[tt][k];
      acc += rv.x * wfs[k][n] + rv.y * wfs[k + 1][n] +
             rv.z * wfs[k + 2][n] + rv.w * wfs[k + 3][n];
    }
    const float v = acc + bfin[n];
    const size_t tok = (size_t)blockIdx.x * 4 + tt;
    P1[tok * 16 + n] = v;
    P2[tok * 16 + n] = v;
  }
}

extern "C" void kernel_launch(void* const* d_in, const int* in_sizes, int n_in,
                              void* d_out, int out_size, void* d_ws, size_t ws_size,
                              hipStream_t stream) {
  const float* inp  = (const float*)d_in[0];
  const float* Wp   = (const float*)d_in[2];
  const float* bp   = (const float*)d_in[3];
  const float* Wq   = (const float*)d_in[4];
  const float* bq   = (const float*)d_in[5];
  const float* Wk   = (const float*)d_in[6];
  const float* bk   = (const float*)d_in[7];
  const float* Wv   = (const float*)d_in[8];
  const float* bv   = (const float*)d_in[9];
  const float* Wo   = (const float*)d_in[10];
  const float* bo   = (const float*)d_in[11];
  const float* g1   = (const float*)d_in[12];
  const float* be1  = (const float*)d_in[13];
  const float* g2   = (const float*)d_in[14];
  const float* be2  = (const float*)d_in[15];
  const float* Wf1  = (const float*)d_in[16];
  const float* bf1  = (const float*)d_in[17];
  const float* Wf2  = (const float*)d_in[18];
  const float* bf2  = (const float*)d_in[19];
  const float* Wfin = (const float*)d_in[20];
  const float* bfin = (const float*)d_in[21];
  (void)in_sizes; (void)n_in; (void)out_size; (void)ws_size;

  float* out = (float*)d_out;
  float* o_pred1 = out;                    // (B,P,S,16)
  float* o_pred2 = out + 262144;
  float* o_k     = out + 524288;           // (B,P,S,512)
  float* o_v     = out + 8912896;
  float* o_r     = out + 17301504;
  float* o_att   = out + 25690112;         // (B,P,S,S)

  // workspace carve-up (~170 MB)
  char* base = (char*)d_ws;
  size_t off = 0;
  auto takeB = [&](size_t bytes) -> char* {
    char* p = base + off;
    off += (bytes + 255) & ~(size_t)255;
    return p;
  };
  float*  Wfold = (float*)takeB((size_t)16 * 1536 * 4);
  float*  bfold = (float*)takeB((size_t)1536 * 4);
  __bf16* Wo_t  = (__bf16*)takeB((size_t)DD * DD * 2);
  __bf16* Wf1_t = (__bf16*)takeB((size_t)DD * DFFX * 2);
  __bf16* Wf2_t = (__bf16*)takeB((size_t)DD * DFFX * 2);
  __bf16* xb    = (__bf16*)takeB((size_t)TT * DD * 2);
  __bf16* qbuf  = (__bf16*)takeB((size_t)TT * DD * 2);
  __bf16* kbuf  = (__bf16*)takeB((size_t)TT * DD * 2);
  __bf16* vbuf  = (__bf16*)takeB((size_t)TT * DD * 2);
  __bf16* vwt   = (__bf16*)takeB((size_t)TT * DD * 2);   // V@Wo transposed [z][D][S]
  __bf16* h1b   = (__bf16*)takeB((size_t)TT * DD * 2);
  __bf16* lninb = (__bf16*)takeB((size_t)TT * DD * 2);
  __bf16* ffb   = (__bf16*)takeB((size_t)TT * DFFX * 2);
  __bf16* pb    = ffb;  // bf16 scores->probs alias FFN scratch (same element
                        // count; pb dead before FFN1 writes ffb)

  // weights -> bf16 transposed [N][K], one merged launch
  transpose_conv3<<<dim3(2304), 256, 0, stream>>>(Wo, Wf1, Wf2, Wo_t, Wf1_t, Wf2_t);

  // fold Wp into Wq/Wk/Wv:  q|k|v = inp @ Wfold + bfold  (K=16)
  fold_kernel<<<dim3(96), 256, 0, stream>>>(Wp, bp, Wq, bq, Wk, bk, Wv, bv,
                                            Wfold, bfold);

  // q,k,v (+ fp32 o_k/o_v) and x residual, one K=16 launch (4 slices)
  smallk_kernel<<<dim3(TT / 16, 4), 256, 0, stream>>>(
      inp, Wfold, bfold, Wp, bp, qbuf, kbuf, vbuf, xb, o_k, o_v);

  // combined: scores -> bf16 pb (tri) AND VWo^T -> vwt, one launch,
  // DEFAULT dispatch (round-robin interleaves tri-heavy m-bands across XCDs)
  attn_prep_kernel<<<dim3(20, 16, BB), 256, 0, stream>>>(
      qbuf, kbuf, vbuf, Wo_t, pb, vwt);

  // softmax: bf16 scores (pb) -> fp32 probs (o_att, zeros above diag) + bf16 pb
  softmax_kernel<<<dim3(TT / 4), 256, 0, stream>>>(o_att, pb);

  // PV' = P @ VWo + bo + x -> LN1 input. 512 blocks (2/CU), greedy balance,
  // DEFAULT dispatch (no remap: chunked remap skews triangular load 4x per XCD)
  gemm128<true, false, true, false><<<dim3(4, 16, BB), 256, 0, stream>>>(
      pb, vwt, bo, xb, lninb, DD, SS,
      (size_t)SS * SS, (size_t)DD * SS, (size_t)SS * DD);

  // LN1
  ln_kernel<<<dim3(TT / 4), 256, 0, stream>>>(lninb, g1, be1, h1b);

  // FFN: uniform work -> keep XCD-chunked swizzle (A-panel L2 reuse)
  gemm128<false, true, false, true><<<dim3(16, 128, 1), 256, 0, stream>>>(
      h1b, Wf1_t, bf1, nullptr, ffb, DFFX, DD, 0, 0, 0);
  gemm128<false, false, true, true><<<dim3(4, 128, 1), 256, 0, stream>>>(
      ffb, Wf2_t, bf2, h1b, lninb, DD, DFFX, 0, 0, 0);

  // fused LN2 -> r (fp32 output) + final projection -> pred (both slots)
  ln_final_kernel<<<dim3(TT / 4), 256, 0, stream>>>(
      lninb, g2, be2, o_r, Wfin, bfin, o_pred1, o_pred2);
}